// Round 1
// baseline (1455.806 us; speedup 1.0000x reference)
//
#include <hip/hip_runtime.h>
#include <math.h>

#define NND 10000
#define NE  160000
#define HD  128
#define NH  (NND*HD)   // 1,280,000

__device__ __forceinline__ float silu_f(float v) {
    return v * (1.0f / (1.0f + __expf(-v)));
}

// ---------------------------------------------------------------------------
// K1: normalize X, decompose into 10 scalar fields [f][n][h]
// fields: 0=I, 1..3 = A vector (A[2,1],A[0,2],A[1,0]), 4..9 = S (00,11,22,01,02,12)
// ---------------------------------------------------------------------------
__global__ __launch_bounds__(256) void node_prep(const float* __restrict__ X,
                                                 float* __restrict__ comp) {
    int idx = blockIdx.x * 256 + threadIdx.x;
    if (idx >= NH) return;
    const float* xp = X + (size_t)idx * 9;
    float x[9];
    #pragma unroll
    for (int i = 0; i < 9; i++) x[i] = xp[i];
    float nsq = 0.f;
    #pragma unroll
    for (int i = 0; i < 9; i++) nsq = fmaf(x[i], x[i], nsq);
    float inv = 1.0f / (nsq + 1.0f);
    #pragma unroll
    for (int i = 0; i < 9; i++) x[i] *= inv;

    float I0  = (x[0] + x[4] + x[8]) * (1.0f / 3.0f);
    float a0  = 0.5f * (x[7] - x[5]);   // A[2,1]
    float a1  = 0.5f * (x[2] - x[6]);   // A[0,2]
    float a2  = 0.5f * (x[3] - x[1]);   // A[1,0]
    float s00 = x[0] - I0;
    float s11 = x[4] - I0;
    float s22 = x[8] - I0;
    float s01 = 0.5f * (x[1] + x[3]);
    float s02 = 0.5f * (x[2] + x[6]);
    float s12 = 0.5f * (x[5] + x[7]);

    comp[0*NH + idx] = I0;
    comp[1*NH + idx] = a0;  comp[2*NH + idx] = a1;  comp[3*NH + idx] = a2;
    comp[4*NH + idx] = s00; comp[5*NH + idx] = s11; comp[6*NH + idx] = s22;
    comp[7*NH + idx] = s01; comp[8*NH + idx] = s02; comp[9*NH + idx] = s12;
}

// ---------------------------------------------------------------------------
// K2: channel mix. comp viewed as [10*NND][128] row-major; group 0 = rows
// [0,N) uses Wt[w0], group 1 = [N,4N) uses Wt[w1], group 2 = [4N,10N) Wt[w2].
// BM=64, BN=128, BK=32, 256 threads, 8x4 micro-tile per thread.
// ---------------------------------------------------------------------------
__global__ __launch_bounds__(256) void mix_gemm(const float* __restrict__ A,
                                                const float* __restrict__ Wt,
                                                float* __restrict__ C,
                                                int w0, int w1, int w2) {
    const int g = blockIdx.y;
    const int baseRow = (g == 0) ? 0   : (g == 1 ? NND     : 4*NND);
    const int Mg      = (g == 0) ? NND : (g == 1 ? 3*NND   : 6*NND);
    const int row0 = blockIdx.x * 64;
    if (row0 >= Mg) return;
    const int wi = (g == 0) ? w0 : (g == 1 ? w1 : w2);
    const float* B  = Wt + (size_t)wi * HD * HD;
    const float* Ab = A + (size_t)baseRow * HD;
    float* Cb = C + (size_t)baseRow * HD;

    __shared__ float As[32][65];     // transposed A tile: As[k][r]
    __shared__ float Bs[32][128];

    const int t  = threadIdx.x;
    const int tx = t & 31;           // cols tx*4 .. tx*4+3
    const int ty = t >> 5;           // rows ty*8 .. ty*8+7

    float acc[8][4];
    #pragma unroll
    for (int i = 0; i < 8; i++)
        #pragma unroll
        for (int j = 0; j < 4; j++) acc[i][j] = 0.0f;

    for (int k0 = 0; k0 < HD; k0 += 32) {
        #pragma unroll
        for (int i = 0; i < 8; i++) {
            int lin = t + 256 * i;
            int r = lin >> 5, kk = lin & 31;
            int rr = row0 + r; if (rr >= Mg) rr = Mg - 1;
            As[kk][r] = Ab[(size_t)rr * HD + k0 + kk];
        }
        #pragma unroll
        for (int i = 0; i < 16; i++) {
            int lin = t + 256 * i;
            int kr = lin >> 7, c = lin & 127;
            Bs[kr][c] = B[(size_t)(k0 + kr) * HD + c];
        }
        __syncthreads();
        #pragma unroll
        for (int k = 0; k < 32; k++) {
            float a[8];
            #pragma unroll
            for (int i = 0; i < 8; i++) a[i] = As[k][ty*8 + i];
            float4 bv = *(const float4*)&Bs[k][tx*4];
            #pragma unroll
            for (int i = 0; i < 8; i++) {
                acc[i][0] = fmaf(a[i], bv.x, acc[i][0]);
                acc[i][1] = fmaf(a[i], bv.y, acc[i][1]);
                acc[i][2] = fmaf(a[i], bv.z, acc[i][2]);
                acc[i][3] = fmaf(a[i], bv.w, acc[i][3]);
            }
        }
        __syncthreads();
    }
    #pragma unroll
    for (int i = 0; i < 8; i++) {
        int rr = row0 + ty*8 + i;
        if (rr < Mg) {
            float4 v = make_float4(acc[i][0], acc[i][1], acc[i][2], acc[i][3]);
            *(float4*)&Cb[(size_t)rr * HD + tx*4] = v;
        }
    }
}

// ---------------------------------------------------------------------------
// K3: fused edge MLP (64->128->256->384, SiLU) + cutoff + gather/scatter.
// 32 edges per block, activations staged in LDS. Yc = post-mix fields
// [10][NH] (gathered at dst), msg accumulated at src via fp32 atomics.
// ---------------------------------------------------------------------------
__global__ __launch_bounds__(256) void edge_mlp_scatter(
    const float* __restrict__ edge_attr, const float* __restrict__ charges,
    const float* __restrict__ edge_weight, const int* __restrict__ edge_index,
    const float* __restrict__ W1, const float* __restrict__ b1,
    const float* __restrict__ W2, const float* __restrict__ b2,
    const float* __restrict__ W3, const float* __restrict__ b3,
    const float* __restrict__ Yc, float* __restrict__ msg)
{
    __shared__ float xs0[32][64];
    __shared__ float x1s[32][128];
    __shared__ float x2s[32][256];
    __shared__ int   srcS[32];
    __shared__ int   dstS[32];
    __shared__ float Cs[32];

    const int t  = threadIdx.x;
    const int e0 = blockIdx.x * 32;

    if (t < 32) {
        int e = e0 + t;
        srcS[t] = edge_index[e];
        dstS[t] = edge_index[NE + e];
        float w = edge_weight[e];
        float c = 0.5f * (cosf(w * (float)(M_PI / 4.5)) + 1.0f);
        Cs[t] = (w < 4.5f) ? c : 0.0f;
    }
    __syncthreads();

    // stage inputs: [attr(32) | charges[src](16) | charges[dst](16)]
    #pragma unroll
    for (int i = 0; i < 8; i++) {
        int lin = t + 256 * i;
        int e = lin >> 6, col = lin & 63;
        float v;
        if (col < 32)      v = edge_attr[(size_t)(e0 + e) * 32 + col];
        else if (col < 48) v = charges[(size_t)srcS[e] * 16 + (col - 32)];
        else               v = charges[(size_t)dstS[e] * 16 + (col - 48)];
        xs0[e][col] = v;
    }
    __syncthreads();

    // ---- layer 1: 64 -> 128 (thread owns cols j, j+64; 8 edges) ----
    {
        const int j  = t & 63;
        const int eh = t >> 6;           // 0..3
        float acc0[8], acc1[8];
        float bb0 = b1[j], bb1 = b1[j + 64];
        #pragma unroll
        for (int i = 0; i < 8; i++) { acc0[i] = bb0; acc1[i] = bb1; }
        for (int k0 = 0; k0 < 64; k0 += 4) {
            float4 xv[8];
            #pragma unroll
            for (int i = 0; i < 8; i++) xv[i] = *(const float4*)&xs0[eh + 4*i][k0];
            #pragma unroll
            for (int kk = 0; kk < 4; kk++) {
                float wA = W1[(size_t)(k0 + kk) * 128 + j];
                float wB = W1[(size_t)(k0 + kk) * 128 + j + 64];
                #pragma unroll
                for (int i = 0; i < 8; i++) {
                    float xval = ((const float*)&xv[i])[kk];
                    acc0[i] = fmaf(xval, wA, acc0[i]);
                    acc1[i] = fmaf(xval, wB, acc1[i]);
                }
            }
        }
        #pragma unroll
        for (int i = 0; i < 8; i++) {
            int e = eh + 4*i;
            x1s[e][j]      = silu_f(acc0[i]);
            x1s[e][j + 64] = silu_f(acc1[i]);
        }
    }
    __syncthreads();

    // ---- layer 2: 128 -> 256 (thread owns cols j, j+128; 16 edges) ----
    {
        const int j  = t & 127;
        const int eh = t >> 7;           // 0..1
        float acc0[16], acc1[16];
        float bb0 = b2[j], bb1 = b2[j + 128];
        #pragma unroll
        for (int i = 0; i < 16; i++) { acc0[i] = bb0; acc1[i] = bb1; }
        for (int k0 = 0; k0 < 128; k0 += 4) {
            float4 xv[16];
            #pragma unroll
            for (int i = 0; i < 16; i++) xv[i] = *(const float4*)&x1s[eh + 2*i][k0];
            #pragma unroll
            for (int kk = 0; kk < 4; kk++) {
                float wA = W2[(size_t)(k0 + kk) * 256 + j];
                float wB = W2[(size_t)(k0 + kk) * 256 + j + 128];
                #pragma unroll
                for (int i = 0; i < 16; i++) {
                    float xval = ((const float*)&xv[i])[kk];
                    acc0[i] = fmaf(xval, wA, acc0[i]);
                    acc1[i] = fmaf(xval, wB, acc1[i]);
                }
            }
        }
        #pragma unroll
        for (int i = 0; i < 16; i++) {
            int e = eh + 2*i;
            x2s[e][j]       = silu_f(acc0[i]);
            x2s[e][j + 128] = silu_f(acc1[i]);
        }
    }
    __syncthreads();

    // ---- layer 3: 256 -> 384 (thread owns cols j, 128+j, 256+j; 16 edges)
    //      + cutoff scale + gather(dst)/atomic-scatter(src) ----
    {
        const int j  = t & 127;
        const int eh = t >> 7;           // 0..1
        float acc0[16], acc1[16], acc2[16];
        float bb0 = b3[j], bb1 = b3[128 + j], bb2 = b3[256 + j];
        #pragma unroll
        for (int i = 0; i < 16; i++) { acc0[i] = bb0; acc1[i] = bb1; acc2[i] = bb2; }
        for (int k0 = 0; k0 < 256; k0 += 4) {
            float4 xv[16];
            #pragma unroll
            for (int i = 0; i < 16; i++) xv[i] = *(const float4*)&x2s[eh + 2*i][k0];
            #pragma unroll
            for (int kk = 0; kk < 4; kk++) {
                float w0v = W3[(size_t)(k0 + kk) * 384 + j];
                float w1v = W3[(size_t)(k0 + kk) * 384 + 128 + j];
                float w2v = W3[(size_t)(k0 + kk) * 384 + 256 + j];
                #pragma unroll
                for (int i = 0; i < 16; i++) {
                    float xval = ((const float*)&xv[i])[kk];
                    acc0[i] = fmaf(xval, w0v, acc0[i]);
                    acc1[i] = fmaf(xval, w1v, acc1[i]);
                    acc2[i] = fmaf(xval, w2v, acc2[i]);
                }
            }
        }
        #pragma unroll
        for (int i = 0; i < 16; i++) {
            int e = eh + 2*i;
            int s = srcS[e], d = dstS[e];
            float cf = Cs[e];
            float v0 = silu_f(acc0[i]) * cf;   // x[:,0,h] -> I message
            float v1 = silu_f(acc1[i]) * cf;   // x[:,1,h] -> A message
            float v2 = silu_f(acc2[i]) * cf;   // x[:,2,h] -> S message
            size_t db = (size_t)d * HD + j;
            size_t sb = (size_t)s * HD + j;
            atomicAdd(&msg[0*NH + sb], v0 * Yc[0*NH + db]);
            #pragma unroll
            for (int cc = 0; cc < 3; cc++)
                atomicAdd(&msg[(1+cc)*NH + sb], v1 * Yc[(1+cc)*NH + db]);
            #pragma unroll
            for (int cc = 0; cc < 6; cc++)
                atomicAdd(&msg[(4+cc)*NH + sb], v2 * Yc[(4+cc)*NH + db]);
        }
    }
}

// ---------------------------------------------------------------------------
// K4: T = msg@Y + Y@msg, decompose, normalize -> premix fields
// ---------------------------------------------------------------------------
__global__ __launch_bounds__(256) void combine(const float* __restrict__ msg,
                                               const float* __restrict__ Yc,
                                               float* __restrict__ pre) {
    int idx = blockIdx.x * 256 + threadIdx.x;
    if (idx >= NH) return;

    float mI  = msg[0*NH + idx];
    float ma0 = msg[1*NH + idx], ma1 = msg[2*NH + idx], ma2 = msg[3*NH + idx];
    float ms00 = msg[4*NH + idx], ms11 = msg[5*NH + idx], ms22 = msg[6*NH + idx];
    float ms01 = msg[7*NH + idx], ms02 = msg[8*NH + idx], ms12 = msg[9*NH + idx];

    float yI  = Yc[0*NH + idx];
    float ya0 = Yc[1*NH + idx], ya1 = Yc[2*NH + idx], ya2 = Yc[3*NH + idx];
    float ys00 = Yc[4*NH + idx], ys11 = Yc[5*NH + idx], ys22 = Yc[6*NH + idx];
    float ys01 = Yc[7*NH + idx], ys02 = Yc[8*NH + idx], ys12 = Yc[9*NH + idx];

    float M[3][3] = {
        { mI + ms00,  ms01 - ma2, ms02 + ma1 },
        { ms01 + ma2, mI + ms11,  ms12 - ma0 },
        { ms02 - ma1, ms12 + ma0, mI + ms22  } };
    float Y[3][3] = {
        { yI + ys00,  ys01 - ya2, ys02 + ya1 },
        { ys01 + ya2, yI + ys11,  ys12 - ya0 },
        { ys02 - ya1, ys12 + ya0, yI + ys22  } };

    float T[3][3];
    #pragma unroll
    for (int r = 0; r < 3; r++)
        #pragma unroll
        for (int c = 0; c < 3; c++) {
            float acc = 0.f;
            #pragma unroll
            for (int k = 0; k < 3; k++)
                acc += M[r][k] * Y[k][c] + Y[r][k] * M[k][c];
            T[r][c] = acc;
        }

    float tr3 = (T[0][0] + T[1][1] + T[2][2]) * (1.0f / 3.0f);
    float nsq = 0.f;
    #pragma unroll
    for (int r = 0; r < 3; r++)
        #pragma unroll
        for (int c = 0; c < 3; c++) nsq = fmaf(T[r][c], T[r][c], nsq);
    float inv = 1.0f / (nsq + 1.0f);

    pre[0*NH + idx] = tr3 * inv;
    pre[1*NH + idx] = 0.5f * (T[2][1] - T[1][2]) * inv;
    pre[2*NH + idx] = 0.5f * (T[0][2] - T[2][0]) * inv;
    pre[3*NH + idx] = 0.5f * (T[1][0] - T[0][1]) * inv;
    pre[4*NH + idx] = (T[0][0] - tr3) * inv;
    pre[5*NH + idx] = (T[1][1] - tr3) * inv;
    pre[6*NH + idx] = (T[2][2] - tr3) * inv;
    pre[7*NH + idx] = 0.5f * (T[0][1] + T[1][0]) * inv;
    pre[8*NH + idx] = 0.5f * (T[0][2] + T[2][0]) * inv;
    pre[9*NH + idx] = 0.5f * (T[1][2] + T[2][1]) * inv;
}

// ---------------------------------------------------------------------------
// K6: dX from postmix fields; out = Xn + dX + dX@dX
// ---------------------------------------------------------------------------
__global__ __launch_bounds__(256) void final_out(const float* __restrict__ post,
                                                 const float* __restrict__ X,
                                                 float* __restrict__ out) {
    int idx = blockIdx.x * 256 + threadIdx.x;
    if (idx >= NH) return;

    float dI  = post[0*NH + idx];
    float da0 = post[1*NH + idx], da1 = post[2*NH + idx], da2 = post[3*NH + idx];
    float ds00 = post[4*NH + idx], ds11 = post[5*NH + idx], ds22 = post[6*NH + idx];
    float ds01 = post[7*NH + idx], ds02 = post[8*NH + idx], ds12 = post[9*NH + idx];

    float D[3][3] = {
        { dI + ds00,  ds01 - da2, ds02 + da1 },
        { ds01 + da2, dI + ds11,  ds12 - da0 },
        { ds02 - da1, ds12 + da0, dI + ds22  } };

    const float* xp = X + (size_t)idx * 9;
    float x[9];
    #pragma unroll
    for (int i = 0; i < 9; i++) x[i] = xp[i];
    float nsq = 0.f;
    #pragma unroll
    for (int i = 0; i < 9; i++) nsq = fmaf(x[i], x[i], nsq);
    float inv = 1.0f / (nsq + 1.0f);

    float* op = out + (size_t)idx * 9;
    #pragma unroll
    for (int r = 0; r < 3; r++)
        #pragma unroll
        for (int c = 0; c < 3; c++) {
            float p = 0.f;
            #pragma unroll
            for (int k = 0; k < 3; k++) p = fmaf(D[r][k], D[k][c], p);
            op[r*3 + c] = x[r*3 + c] * inv + D[r][c] + p;
        }
}

// ---------------------------------------------------------------------------
extern "C" void kernel_launch(void* const* d_in, const int* in_sizes, int n_in,
                              void* d_out, int out_size, void* d_ws, size_t ws_size,
                              hipStream_t stream) {
    const float* X       = (const float*)d_in[0];
    const float* charges = (const float*)d_in[1];
    const float* ew      = (const float*)d_in[2];
    const float* ea      = (const float*)d_in[3];
    const float* W1      = (const float*)d_in[4];
    const float* b1      = (const float*)d_in[5];
    const float* W2      = (const float*)d_in[6];
    const float* b2      = (const float*)d_in[7];
    const float* W3      = (const float*)d_in[8];
    const float* b3      = (const float*)d_in[9];
    const float* Wt      = (const float*)d_in[10];
    const int*   eidx    = (const int*)d_in[11];
    float* out = (float*)d_out;

    float* compA = (float*)d_ws;                    // premix fields   (51.2 MB)
    float* compB = compA + (size_t)10 * NH;         // postmix / Y     (51.2 MB)
    float* compM = compB + (size_t)10 * NH;         // message accum   (51.2 MB)

    hipMemsetAsync(compM, 0, (size_t)10 * NH * sizeof(float), stream);

    node_prep<<<NH / 256, 256, 0, stream>>>(X, compA);

    dim3 gmix((6 * NND + 63) / 64, 3);
    mix_gemm<<<gmix, 256, 0, stream>>>(compA, Wt, compB, 0, 1, 2);

    edge_mlp_scatter<<<NE / 32, 256, 0, stream>>>(ea, charges, ew, eidx,
                                                  W1, b1, W2, b2, W3, b3,
                                                  compB, compM);

    combine<<<NH / 256, 256, 0, stream>>>(compM, compB, compA);

    mix_gemm<<<gmix, 256, 0, stream>>>(compA, Wt, compB, 3, 4, 5);

    final_out<<<NH / 256, 256, 0, stream>>>(compB, X, out);
}

// Round 2
// 1411.385 us; speedup vs baseline: 1.0315x; 1.0315x over previous
//
#include <hip/hip_runtime.h>
#include <math.h>

#define NND 10000
#define NE  160000
#define HD  128
#define NH  (NND*HD)   // 1,280,000

typedef _Float16 f16;
typedef _Float16 half8 __attribute__((ext_vector_type(8)));
typedef float floatx4 __attribute__((ext_vector_type(4)));

__device__ __forceinline__ float silu_f(float v) {
    return v * (1.0f / (1.0f + __expf(-v)));
}

// ---------------------------------------------------------------------------
// K0: weights -> fp16, transposed to [N][K] for contiguous B-fragment loads
// ---------------------------------------------------------------------------
__global__ __launch_bounds__(256) void w_prep(const float* __restrict__ W1,
                                              const float* __restrict__ W2,
                                              const float* __restrict__ W3,
                                              f16* __restrict__ w1t,
                                              f16* __restrict__ w2t,
                                              f16* __restrict__ w3t) {
    int id = blockIdx.x * 256 + threadIdx.x;
    if (id < 128*64) { int n = id >> 6, k = id & 63;  w1t[id] = (f16)W1[k*128 + n]; return; }
    id -= 128*64;
    if (id < 256*128) { int n = id >> 7, k = id & 127; w2t[id] = (f16)W2[k*256 + n]; return; }
    id -= 256*128;
    if (id < 384*256) { int n = id >> 8, k = id & 255; w3t[id] = (f16)W3[k*384 + n]; }
}

// ---------------------------------------------------------------------------
// K1: normalize X, decompose into 10 scalar fields [f][n][h]
// ---------------------------------------------------------------------------
__global__ __launch_bounds__(256) void node_prep(const float* __restrict__ X,
                                                 float* __restrict__ comp) {
    int idx = blockIdx.x * 256 + threadIdx.x;
    if (idx >= NH) return;
    const float* xp = X + (size_t)idx * 9;
    float x[9];
    #pragma unroll
    for (int i = 0; i < 9; i++) x[i] = xp[i];
    float nsq = 0.f;
    #pragma unroll
    for (int i = 0; i < 9; i++) nsq = fmaf(x[i], x[i], nsq);
    float inv = 1.0f / (nsq + 1.0f);
    #pragma unroll
    for (int i = 0; i < 9; i++) x[i] *= inv;

    float I0  = (x[0] + x[4] + x[8]) * (1.0f / 3.0f);
    float a0  = 0.5f * (x[7] - x[5]);
    float a1  = 0.5f * (x[2] - x[6]);
    float a2  = 0.5f * (x[3] - x[1]);
    float s00 = x[0] - I0;
    float s11 = x[4] - I0;
    float s22 = x[8] - I0;
    float s01 = 0.5f * (x[1] + x[3]);
    float s02 = 0.5f * (x[2] + x[6]);
    float s12 = 0.5f * (x[5] + x[7]);

    comp[0*NH + idx] = I0;
    comp[1*NH + idx] = a0;  comp[2*NH + idx] = a1;  comp[3*NH + idx] = a2;
    comp[4*NH + idx] = s00; comp[5*NH + idx] = s11; comp[6*NH + idx] = s22;
    comp[7*NH + idx] = s01; comp[8*NH + idx] = s02; comp[9*NH + idx] = s12;
}

// ---------------------------------------------------------------------------
// K2: channel mix GEMM (fp32 VALU), [10*NND][128] x [128][128] grouped
// ---------------------------------------------------------------------------
__global__ __launch_bounds__(256) void mix_gemm(const float* __restrict__ A,
                                                const float* __restrict__ Wt,
                                                float* __restrict__ C,
                                                int w0, int w1, int w2) {
    const int g = blockIdx.y;
    const int baseRow = (g == 0) ? 0   : (g == 1 ? NND     : 4*NND);
    const int Mg      = (g == 0) ? NND : (g == 1 ? 3*NND   : 6*NND);
    const int row0 = blockIdx.x * 64;
    if (row0 >= Mg) return;
    const int wi = (g == 0) ? w0 : (g == 1 ? w1 : w2);
    const float* B  = Wt + (size_t)wi * HD * HD;
    const float* Ab = A + (size_t)baseRow * HD;
    float* Cb = C + (size_t)baseRow * HD;

    __shared__ float As[32][65];
    __shared__ float Bs[32][128];

    const int t  = threadIdx.x;
    const int tx = t & 31;
    const int ty = t >> 5;

    float acc[8][4];
    #pragma unroll
    for (int i = 0; i < 8; i++)
        #pragma unroll
        for (int j = 0; j < 4; j++) acc[i][j] = 0.0f;

    for (int k0 = 0; k0 < HD; k0 += 32) {
        #pragma unroll
        for (int i = 0; i < 8; i++) {
            int lin = t + 256 * i;
            int r = lin >> 5, kk = lin & 31;
            int rr = row0 + r; if (rr >= Mg) rr = Mg - 1;
            As[kk][r] = Ab[(size_t)rr * HD + k0 + kk];
        }
        #pragma unroll
        for (int i = 0; i < 16; i++) {
            int lin = t + 256 * i;
            int kr = lin >> 7, c = lin & 127;
            Bs[kr][c] = B[(size_t)(k0 + kr) * HD + c];
        }
        __syncthreads();
        #pragma unroll
        for (int k = 0; k < 32; k++) {
            float a[8];
            #pragma unroll
            for (int i = 0; i < 8; i++) a[i] = As[k][ty*8 + i];
            float4 bv = *(const float4*)&Bs[k][tx*4];
            #pragma unroll
            for (int i = 0; i < 8; i++) {
                acc[i][0] = fmaf(a[i], bv.x, acc[i][0]);
                acc[i][1] = fmaf(a[i], bv.y, acc[i][1]);
                acc[i][2] = fmaf(a[i], bv.z, acc[i][2]);
                acc[i][3] = fmaf(a[i], bv.w, acc[i][3]);
            }
        }
        __syncthreads();
    }
    #pragma unroll
    for (int i = 0; i < 8; i++) {
        int rr = row0 + ty*8 + i;
        if (rr < Mg) {
            float4 v = make_float4(acc[i][0], acc[i][1], acc[i][2], acc[i][3]);
            *(float4*)&Cb[(size_t)rr * HD + tx*4] = v;
        }
    }
}

// ---------------------------------------------------------------------------
// K3: fused edge MLP via fp16 MFMA (64->128->256->384) + cutoff + scatter.
// 64 edges/block, 4 waves. Activations in LDS fp16, rows padded +8 f16 (16B)
// to break the stride bank conflict while keeping 16B alignment.
// MFMA 16x16x32_f16: A row=lane&15, k=(lane>>4)*8+j; B col=lane&15, same k;
// D col=lane&15, row=(lane>>4)*4+reg.
// ---------------------------------------------------------------------------
__global__ __launch_bounds__(256, 2) void edge_mlp_mfma(
    const float* __restrict__ edge_attr, const float* __restrict__ charges,
    const float* __restrict__ edge_weight, const int* __restrict__ edge_index,
    const f16* __restrict__ W1t, const float* __restrict__ b1,
    const f16* __restrict__ W2t, const float* __restrict__ b2,
    const f16* __restrict__ W3t, const float* __restrict__ b3,
    const float* __restrict__ Yc, float* __restrict__ msg)
{
    __shared__ f16 x0s[64*72];    //  9216 B (K=64,  pad->72)
    __shared__ f16 x1s[64*136];   // 17408 B (K=128, pad->136)
    __shared__ f16 x2s[64*264];   // 33792 B (K=256, pad->264)
    __shared__ int   srcS[64];
    __shared__ int   dstS[64];
    __shared__ float Cs[64];

    const int t   = threadIdx.x;
    const int e0  = blockIdx.x * 64;
    const int l   = t & 63;
    const int wid = t >> 6;
    const int lr  = l & 15;
    const int lh  = l >> 4;

    if (t < 64) {
        int e = e0 + t;
        srcS[t] = edge_index[e];
        dstS[t] = edge_index[NE + e];
        float w = edge_weight[e];
        float c = 0.5f * (cosf(w * (float)(M_PI / 4.5)) + 1.0f);
        Cs[t] = (w < 4.5f) ? c : 0.0f;
    }
    __syncthreads();

    // stage inputs as fp16: [attr(32) | charges[src](16) | charges[dst](16)]
    #pragma unroll
    for (int i = 0; i < 16; i++) {
        int lin = t + 256 * i;
        int e = lin >> 6, col = lin & 63;
        float v;
        if (col < 32)      v = edge_attr[(size_t)(e0 + e) * 32 + col];
        else if (col < 48) v = charges[(size_t)srcS[e] * 16 + (col - 32)];
        else               v = charges[(size_t)dstS[e] * 16 + (col - 48)];
        x0s[e * 72 + col] = (f16)v;
    }
    __syncthreads();

    // ---- layer 1: 64x64 @ 64x128 ----
    {
        floatx4 acc[2][4];
        #pragma unroll
        for (int n = 0; n < 2; n++)
            #pragma unroll
            for (int m = 0; m < 4; m++) acc[n][m] = (floatx4)0.0f;

        #pragma unroll
        for (int k0 = 0; k0 < 64; k0 += 32) {
            half8 a[4];
            #pragma unroll
            for (int m = 0; m < 4; m++)
                a[m] = *(const half8*)&x0s[(m*16 + lr)*72 + k0 + lh*8];
            #pragma unroll
            for (int n = 0; n < 2; n++) {
                int colb = wid*32 + n*16 + lr;
                half8 b = *(const half8*)&W1t[(size_t)colb*64 + k0 + lh*8];
                #pragma unroll
                for (int m = 0; m < 4; m++)
                    acc[n][m] = __builtin_amdgcn_mfma_f32_16x16x32_f16(a[m], b, acc[n][m], 0, 0, 0);
            }
        }
        #pragma unroll
        for (int n = 0; n < 2; n++) {
            int col = wid*32 + n*16 + lr;
            float bb = b1[col];
            #pragma unroll
            for (int m = 0; m < 4; m++)
                #pragma unroll
                for (int r = 0; r < 4; r++) {
                    int row = m*16 + lh*4 + r;
                    x1s[row*136 + col] = (f16)silu_f(acc[n][m][r] + bb);
                }
        }
    }
    __syncthreads();

    // ---- layer 2: 64x128 @ 128x256 ----
    {
        floatx4 acc[4][4];
        #pragma unroll
        for (int n = 0; n < 4; n++)
            #pragma unroll
            for (int m = 0; m < 4; m++) acc[n][m] = (floatx4)0.0f;

        #pragma unroll
        for (int k0 = 0; k0 < 128; k0 += 32) {
            half8 a[4];
            #pragma unroll
            for (int m = 0; m < 4; m++)
                a[m] = *(const half8*)&x1s[(m*16 + lr)*136 + k0 + lh*8];
            #pragma unroll
            for (int n = 0; n < 4; n++) {
                int colb = wid*64 + n*16 + lr;
                half8 b = *(const half8*)&W2t[(size_t)colb*128 + k0 + lh*8];
                #pragma unroll
                for (int m = 0; m < 4; m++)
                    acc[n][m] = __builtin_amdgcn_mfma_f32_16x16x32_f16(a[m], b, acc[n][m], 0, 0, 0);
            }
        }
        #pragma unroll
        for (int n = 0; n < 4; n++) {
            int col = wid*64 + n*16 + lr;
            float bb = b2[col];
            #pragma unroll
            for (int m = 0; m < 4; m++)
                #pragma unroll
                for (int r = 0; r < 4; r++) {
                    int row = m*16 + lh*4 + r;
                    x2s[row*264 + col] = (f16)silu_f(acc[n][m][r] + bb);
                }
        }
    }
    __syncthreads();

    // ---- layer 3: 64x256 @ 256x384, then cutoff + gather/scatter ----
    {
        floatx4 acc[6][4];
        #pragma unroll
        for (int n = 0; n < 6; n++)
            #pragma unroll
            for (int m = 0; m < 4; m++) acc[n][m] = (floatx4)0.0f;

        #pragma unroll
        for (int k0 = 0; k0 < 256; k0 += 32) {
            half8 a[4];
            #pragma unroll
            for (int m = 0; m < 4; m++)
                a[m] = *(const half8*)&x2s[(m*16 + lr)*264 + k0 + lh*8];
            #pragma unroll
            for (int n = 0; n < 6; n++) {
                int colb = wid*96 + n*16 + lr;
                half8 b = *(const half8*)&W3t[(size_t)colb*256 + k0 + lh*8];
                #pragma unroll
                for (int m = 0; m < 4; m++)
                    acc[n][m] = __builtin_amdgcn_mfma_f32_16x16x32_f16(a[m], b, acc[n][m], 0, 0, 0);
            }
        }

        #pragma unroll
        for (int n = 0; n < 6; n++) {
            int col = wid*96 + n*16 + lr;
            int g = col >> 7;           // wave-uniform: 0=I, 1=A, 2=S
            int h = col & 127;
            float bb = b3[col];
            #pragma unroll
            for (int m = 0; m < 4; m++) {
                #pragma unroll
                for (int r = 0; r < 4; r++) {
                    int e = m*16 + lh*4 + r;
                    float v = silu_f(acc[n][m][r] + bb) * Cs[e];
                    int s = srcS[e], d = dstS[e];
                    size_t sb = (size_t)s * HD + h;
                    size_t db = (size_t)d * HD + h;
                    if (g == 0) {
                        atomicAdd(&msg[sb], v * Yc[db]);
                    } else if (g == 1) {
                        #pragma unroll
                        for (int cc = 0; cc < 3; cc++)
                            atomicAdd(&msg[(1+cc)*(size_t)NH + sb], v * Yc[(1+cc)*(size_t)NH + db]);
                    } else {
                        #pragma unroll
                        for (int cc = 0; cc < 6; cc++)
                            atomicAdd(&msg[(4+cc)*(size_t)NH + sb], v * Yc[(4+cc)*(size_t)NH + db]);
                    }
                }
            }
        }
    }
}

// ---------------------------------------------------------------------------
// K4: T = msg@Y + Y@msg, decompose, normalize -> premix fields
// ---------------------------------------------------------------------------
__global__ __launch_bounds__(256) void combine(const float* __restrict__ msg,
                                               const float* __restrict__ Yc,
                                               float* __restrict__ pre) {
    int idx = blockIdx.x * 256 + threadIdx.x;
    if (idx >= NH) return;

    float mI  = msg[0*NH + idx];
    float ma0 = msg[1*NH + idx], ma1 = msg[2*NH + idx], ma2 = msg[3*NH + idx];
    float ms00 = msg[4*NH + idx], ms11 = msg[5*NH + idx], ms22 = msg[6*NH + idx];
    float ms01 = msg[7*NH + idx], ms02 = msg[8*NH + idx], ms12 = msg[9*NH + idx];

    float yI  = Yc[0*NH + idx];
    float ya0 = Yc[1*NH + idx], ya1 = Yc[2*NH + idx], ya2 = Yc[3*NH + idx];
    float ys00 = Yc[4*NH + idx], ys11 = Yc[5*NH + idx], ys22 = Yc[6*NH + idx];
    float ys01 = Yc[7*NH + idx], ys02 = Yc[8*NH + idx], ys12 = Yc[9*NH + idx];

    float M[3][3] = {
        { mI + ms00,  ms01 - ma2, ms02 + ma1 },
        { ms01 + ma2, mI + ms11,  ms12 - ma0 },
        { ms02 - ma1, ms12 + ma0, mI + ms22  } };
    float Y[3][3] = {
        { yI + ys00,  ys01 - ya2, ys02 + ya1 },
        { ys01 + ya2, yI + ys11,  ys12 - ya0 },
        { ys02 - ya1, ys12 + ya0, yI + ys22  } };

    float T[3][3];
    #pragma unroll
    for (int r = 0; r < 3; r++)
        #pragma unroll
        for (int c = 0; c < 3; c++) {
            float acc = 0.f;
            #pragma unroll
            for (int k = 0; k < 3; k++)
                acc += M[r][k] * Y[k][c] + Y[r][k] * M[k][c];
            T[r][c] = acc;
        }

    float tr3 = (T[0][0] + T[1][1] + T[2][2]) * (1.0f / 3.0f);
    float nsq = 0.f;
    #pragma unroll
    for (int r = 0; r < 3; r++)
        #pragma unroll
        for (int c = 0; c < 3; c++) nsq = fmaf(T[r][c], T[r][c], nsq);
    float inv = 1.0f / (nsq + 1.0f);

    pre[0*NH + idx] = tr3 * inv;
    pre[1*NH + idx] = 0.5f * (T[2][1] - T[1][2]) * inv;
    pre[2*NH + idx] = 0.5f * (T[0][2] - T[2][0]) * inv;
    pre[3*NH + idx] = 0.5f * (T[1][0] - T[0][1]) * inv;
    pre[4*NH + idx] = (T[0][0] - tr3) * inv;
    pre[5*NH + idx] = (T[1][1] - tr3) * inv;
    pre[6*NH + idx] = (T[2][2] - tr3) * inv;
    pre[7*NH + idx] = 0.5f * (T[0][1] + T[1][0]) * inv;
    pre[8*NH + idx] = 0.5f * (T[0][2] + T[2][0]) * inv;
    pre[9*NH + idx] = 0.5f * (T[1][2] + T[2][1]) * inv;
}

// ---------------------------------------------------------------------------
// K6: dX from postmix fields; out = Xn + dX + dX@dX
// ---------------------------------------------------------------------------
__global__ __launch_bounds__(256) void final_out(const float* __restrict__ post,
                                                 const float* __restrict__ X,
                                                 float* __restrict__ out) {
    int idx = blockIdx.x * 256 + threadIdx.x;
    if (idx >= NH) return;

    float dI  = post[0*NH + idx];
    float da0 = post[1*NH + idx], da1 = post[2*NH + idx], da2 = post[3*NH + idx];
    float ds00 = post[4*NH + idx], ds11 = post[5*NH + idx], ds22 = post[6*NH + idx];
    float ds01 = post[7*NH + idx], ds02 = post[8*NH + idx], ds12 = post[9*NH + idx];

    float D[3][3] = {
        { dI + ds00,  ds01 - da2, ds02 + da1 },
        { ds01 + da2, dI + ds11,  ds12 - da0 },
        { ds02 - da1, ds12 + da0, dI + ds22  } };

    const float* xp = X + (size_t)idx * 9;
    float x[9];
    #pragma unroll
    for (int i = 0; i < 9; i++) x[i] = xp[i];
    float nsq = 0.f;
    #pragma unroll
    for (int i = 0; i < 9; i++) nsq = fmaf(x[i], x[i], nsq);
    float inv = 1.0f / (nsq + 1.0f);

    float* op = out + (size_t)idx * 9;
    #pragma unroll
    for (int r = 0; r < 3; r++)
        #pragma unroll
        for (int c = 0; c < 3; c++) {
            float p = 0.f;
            #pragma unroll
            for (int k = 0; k < 3; k++) p = fmaf(D[r][k], D[k][c], p);
            op[r*3 + c] = x[r*3 + c] * inv + D[r][c] + p;
        }
}

// ---------------------------------------------------------------------------
extern "C" void kernel_launch(void* const* d_in, const int* in_sizes, int n_in,
                              void* d_out, int out_size, void* d_ws, size_t ws_size,
                              hipStream_t stream) {
    const float* X       = (const float*)d_in[0];
    const float* charges = (const float*)d_in[1];
    const float* ew      = (const float*)d_in[2];
    const float* ea      = (const float*)d_in[3];
    const float* W1      = (const float*)d_in[4];
    const float* b1      = (const float*)d_in[5];
    const float* W2      = (const float*)d_in[6];
    const float* b2      = (const float*)d_in[7];
    const float* W3      = (const float*)d_in[8];
    const float* b3      = (const float*)d_in[9];
    const float* Wt      = (const float*)d_in[10];
    const int*   eidx    = (const int*)d_in[11];
    float* out = (float*)d_out;

    float* compA = (float*)d_ws;                    // premix fields   (51.2 MB)
    float* compB = compA + (size_t)10 * NH;         // postmix / Y     (51.2 MB)
    float* compM = compB + (size_t)10 * NH;         // message accum   (51.2 MB)
    f16*   w1t   = (f16*)(compM + (size_t)10 * NH); // fp16 weights (272 KB)
    f16*   w2t   = w1t + 128*64;
    f16*   w3t   = w2t + 256*128;

    hipMemsetAsync(compM, 0, (size_t)10 * NH * sizeof(float), stream);

    w_prep<<<544, 256, 0, stream>>>(W1, W2, W3, w1t, w2t, w3t);

    node_prep<<<NH / 256, 256, 0, stream>>>(X, compA);

    dim3 gmix((6 * NND + 63) / 64, 3);
    mix_gemm<<<gmix, 256, 0, stream>>>(compA, Wt, compB, 0, 1, 2);

    edge_mlp_mfma<<<NE / 64, 256, 0, stream>>>(ea, charges, ew, eidx,
                                               w1t, b1, w2t, b2, w3t, b3,
                                               compB, compM);

    combine<<<NH / 256, 256, 0, stream>>>(compM, compB, compA);

    mix_gemm<<<gmix, 256, 0, stream>>>(compA, Wt, compB, 3, 4, 5);

    final_out<<<NH / 256, 256, 0, stream>>>(compB, X, out);
}

// Round 3
// 1411.228 us; speedup vs baseline: 1.0316x; 1.0001x over previous
//
#include <hip/hip_runtime.h>
#include <math.h>

#define NND 10000
#define NE  160000
#define HD  128
#define NH  (NND*HD)   // 1,280,000
#define R_MAX 11       // LDS run-accumulator slots

typedef _Float16 f16;
typedef _Float16 half8 __attribute__((ext_vector_type(8)));
typedef float floatx4 __attribute__((ext_vector_type(4)));

__device__ __forceinline__ float silu_f(float v) {
    return v * (1.0f / (1.0f + __expf(-v)));
}

// ---------------------------------------------------------------------------
// K0: weights -> fp16, transposed to [N][K] for contiguous B-fragment loads
// ---------------------------------------------------------------------------
__global__ __launch_bounds__(256) void w_prep(const float* __restrict__ W1,
                                              const float* __restrict__ W2,
                                              const float* __restrict__ W3,
                                              f16* __restrict__ w1t,
                                              f16* __restrict__ w2t,
                                              f16* __restrict__ w3t) {
    int id = blockIdx.x * 256 + threadIdx.x;
    if (id < 128*64) { int n = id >> 6, k = id & 63;  w1t[id] = (f16)W1[k*128 + n]; return; }
    id -= 128*64;
    if (id < 256*128) { int n = id >> 7, k = id & 127; w2t[id] = (f16)W2[k*256 + n]; return; }
    id -= 256*128;
    if (id < 384*256) { int n = id >> 8, k = id & 255; w3t[id] = (f16)W3[k*384 + n]; }
}

// ---------------------------------------------------------------------------
// Counting sort of edges by src: histogram -> scan -> scatter
// ---------------------------------------------------------------------------
__global__ __launch_bounds__(256) void hist_kernel(const int* __restrict__ eidx,
                                                   int* __restrict__ hist) {
    int e = blockIdx.x * 256 + threadIdx.x;
    if (e < NE) atomicAdd(&hist[eidx[e]], 1);
}

__global__ __launch_bounds__(1024) void scan_kernel(const int* __restrict__ hist,
                                                    int* __restrict__ offs,
                                                    int* __restrict__ cursor) {
    __shared__ int sums[1024];
    int t = threadIdx.x;
    int base = t * 10;
    int loc[10]; int s = 0;
    #pragma unroll
    for (int i = 0; i < 10; i++) {
        int v = (base + i < NND) ? hist[base + i] : 0;
        loc[i] = s; s += v;
    }
    sums[t] = s;
    __syncthreads();
    for (int off = 1; off < 1024; off <<= 1) {
        int v = (t >= off) ? sums[t - off] : 0;
        __syncthreads();
        sums[t] += v;
        __syncthreads();
    }
    int basesum = (t > 0) ? sums[t - 1] : 0;
    #pragma unroll
    for (int i = 0; i < 10; i++)
        if (base + i < NND) { offs[base + i] = basesum + loc[i]; cursor[base + i] = basesum + loc[i]; }
}

__global__ __launch_bounds__(256) void scatter_kernel(const int* __restrict__ eidx,
                                                      int* __restrict__ cursor,
                                                      int* __restrict__ perm,
                                                      int* __restrict__ ssrc,
                                                      int* __restrict__ sdst) {
    int e = blockIdx.x * 256 + threadIdx.x;
    if (e >= NE) return;
    int s = eidx[e], d = eidx[NE + e];
    int pos = atomicAdd(&cursor[s], 1);
    perm[pos] = e; ssrc[pos] = s; sdst[pos] = d;
}

// ---------------------------------------------------------------------------
// K1: normalize X, decompose into 10 scalar fields [f][n][h]
// ---------------------------------------------------------------------------
__global__ __launch_bounds__(256) void node_prep(const float* __restrict__ X,
                                                 float* __restrict__ comp) {
    int idx = blockIdx.x * 256 + threadIdx.x;
    if (idx >= NH) return;
    const float* xp = X + (size_t)idx * 9;
    float x[9];
    #pragma unroll
    for (int i = 0; i < 9; i++) x[i] = xp[i];
    float nsq = 0.f;
    #pragma unroll
    for (int i = 0; i < 9; i++) nsq = fmaf(x[i], x[i], nsq);
    float inv = 1.0f / (nsq + 1.0f);
    #pragma unroll
    for (int i = 0; i < 9; i++) x[i] *= inv;

    float I0  = (x[0] + x[4] + x[8]) * (1.0f / 3.0f);
    float a0  = 0.5f * (x[7] - x[5]);
    float a1  = 0.5f * (x[2] - x[6]);
    float a2  = 0.5f * (x[3] - x[1]);
    float s00 = x[0] - I0;
    float s11 = x[4] - I0;
    float s22 = x[8] - I0;
    float s01 = 0.5f * (x[1] + x[3]);
    float s02 = 0.5f * (x[2] + x[6]);
    float s12 = 0.5f * (x[5] + x[7]);

    comp[0*NH + idx] = I0;
    comp[1*NH + idx] = a0;  comp[2*NH + idx] = a1;  comp[3*NH + idx] = a2;
    comp[4*NH + idx] = s00; comp[5*NH + idx] = s11; comp[6*NH + idx] = s22;
    comp[7*NH + idx] = s01; comp[8*NH + idx] = s02; comp[9*NH + idx] = s12;
}

// ---------------------------------------------------------------------------
// K2: channel mix GEMM (fp32 VALU), [10*NND][128] x [128][128] grouped
// ---------------------------------------------------------------------------
__global__ __launch_bounds__(256) void mix_gemm(const float* __restrict__ A,
                                                const float* __restrict__ Wt,
                                                float* __restrict__ C,
                                                int w0, int w1, int w2) {
    const int g = blockIdx.y;
    const int baseRow = (g == 0) ? 0   : (g == 1 ? NND     : 4*NND);
    const int Mg      = (g == 0) ? NND : (g == 1 ? 3*NND   : 6*NND);
    const int row0 = blockIdx.x * 64;
    if (row0 >= Mg) return;
    const int wi = (g == 0) ? w0 : (g == 1 ? w1 : w2);
    const float* B  = Wt + (size_t)wi * HD * HD;
    const float* Ab = A + (size_t)baseRow * HD;
    float* Cb = C + (size_t)baseRow * HD;

    __shared__ float As[32][65];
    __shared__ float Bs[32][128];

    const int t  = threadIdx.x;
    const int tx = t & 31;
    const int ty = t >> 5;

    float acc[8][4];
    #pragma unroll
    for (int i = 0; i < 8; i++)
        #pragma unroll
        for (int j = 0; j < 4; j++) acc[i][j] = 0.0f;

    for (int k0 = 0; k0 < HD; k0 += 32) {
        #pragma unroll
        for (int i = 0; i < 8; i++) {
            int lin = t + 256 * i;
            int r = lin >> 5, kk = lin & 31;
            int rr = row0 + r; if (rr >= Mg) rr = Mg - 1;
            As[kk][r] = Ab[(size_t)rr * HD + k0 + kk];
        }
        #pragma unroll
        for (int i = 0; i < 16; i++) {
            int lin = t + 256 * i;
            int kr = lin >> 7, c = lin & 127;
            Bs[kr][c] = B[(size_t)(k0 + kr) * HD + c];
        }
        __syncthreads();
        #pragma unroll
        for (int k = 0; k < 32; k++) {
            float a[8];
            #pragma unroll
            for (int i = 0; i < 8; i++) a[i] = As[k][ty*8 + i];
            float4 bv = *(const float4*)&Bs[k][tx*4];
            #pragma unroll
            for (int i = 0; i < 8; i++) {
                acc[i][0] = fmaf(a[i], bv.x, acc[i][0]);
                acc[i][1] = fmaf(a[i], bv.y, acc[i][1]);
                acc[i][2] = fmaf(a[i], bv.z, acc[i][2]);
                acc[i][3] = fmaf(a[i], bv.w, acc[i][3]);
            }
        }
        __syncthreads();
    }
    #pragma unroll
    for (int i = 0; i < 8; i++) {
        int rr = row0 + ty*8 + i;
        if (rr < Mg) {
            float4 v = make_float4(acc[i][0], acc[i][1], acc[i][2], acc[i][3]);
            *(float4*)&Cb[(size_t)rr * HD + tx*4] = v;
        }
    }
}

// ---------------------------------------------------------------------------
// K3: fused edge MLP via fp16 MFMA over SORTED edges + segmented scatter.
// 64 sorted edges/block, 4 waves. LDS activation buffers aliased with the
// run-accumulator (used after the last MFMA consumes x2s).
// ---------------------------------------------------------------------------
__global__ __launch_bounds__(256, 2) void edge_mlp_sorted(
    const float* __restrict__ edge_attr, const float* __restrict__ charges,
    const float* __restrict__ edge_weight,
    const int* __restrict__ perm, const int* __restrict__ ssrc, const int* __restrict__ sdst,
    const f16* __restrict__ W1t, const float* __restrict__ b1,
    const f16* __restrict__ W2t, const float* __restrict__ b2,
    const f16* __restrict__ W3t, const float* __restrict__ b3,
    const float* __restrict__ Yc, float* __restrict__ msg)
{
    __shared__ __align__(16) char pool[60416];
    f16* x0s = (f16*)pool;                 //  9216 B (K=64,  row stride 72)
    f16* x1s = (f16*)(pool + 9216);        // 17408 B (K=128, row stride 136)
    f16* x2s = (f16*)(pool + 26624);       // 33792 B (K=256, row stride 264)
    float* accum = (float*)pool;           // 11*1280*4 = 56320 B (aliases x*)

    __shared__ int   srcS[64];
    __shared__ int   dstS[64];
    __shared__ int   permS[64];
    __shared__ int   ridS[64];
    __shared__ int   runSrc[64];
    __shared__ float Cs[64];
    __shared__ int   nrunsS;

    const int t   = threadIdx.x;
    const int e0  = blockIdx.x * 64;
    const int l   = t & 63;
    const int wid = t >> 6;
    const int lr  = l & 15;
    const int lh  = l >> 4;

    if (t < 64) {
        int p  = e0 + t;
        int eo = perm[p];
        int s  = ssrc[p];
        permS[t] = eo;
        srcS[t]  = s;
        dstS[t]  = sdst[p];
        float w = edge_weight[eo];
        float c = 0.5f * (cosf(w * (float)(M_PI / 4.5)) + 1.0f);
        Cs[t] = (w < 4.5f) ? c : 0.0f;
        // run-id per edge within the block (edges sorted by src)
        int prev = __shfl_up(s, 1);
        bool flag = (t == 0) || (s != prev);
        unsigned long long mask = __ballot(flag);
        int rid = __popcll(mask & ((2ull << t) - 1)) - 1;
        ridS[t] = rid;
        if (flag) runSrc[rid] = s;
        if (t == 63) nrunsS = (int)__popcll(mask);
    }
    __syncthreads();

    // stage inputs as fp16: [attr(32) | charges[src](16) | charges[dst](16)]
    #pragma unroll
    for (int i = 0; i < 16; i++) {
        int lin = t + 256 * i;
        int e = lin >> 6, col = lin & 63;
        float v;
        if (col < 32)      v = edge_attr[(size_t)permS[e] * 32 + col];
        else if (col < 48) v = charges[(size_t)srcS[e] * 16 + (col - 32)];
        else               v = charges[(size_t)dstS[e] * 16 + (col - 48)];
        x0s[e * 72 + col] = (f16)v;
    }
    __syncthreads();

    // ---- layer 1: 64x64 @ 64x128 ----
    {
        floatx4 acc[2][4];
        #pragma unroll
        for (int n = 0; n < 2; n++)
            #pragma unroll
            for (int m = 0; m < 4; m++) acc[n][m] = (floatx4)0.0f;

        #pragma unroll
        for (int k0 = 0; k0 < 64; k0 += 32) {
            half8 a[4];
            #pragma unroll
            for (int m = 0; m < 4; m++)
                a[m] = *(const half8*)&x0s[(m*16 + lr)*72 + k0 + lh*8];
            #pragma unroll
            for (int n = 0; n < 2; n++) {
                int colb = wid*32 + n*16 + lr;
                half8 b = *(const half8*)&W1t[(size_t)colb*64 + k0 + lh*8];
                #pragma unroll
                for (int m = 0; m < 4; m++)
                    acc[n][m] = __builtin_amdgcn_mfma_f32_16x16x32_f16(a[m], b, acc[n][m], 0, 0, 0);
            }
        }
        #pragma unroll
        for (int n = 0; n < 2; n++) {
            int col = wid*32 + n*16 + lr;
            float bb = b1[col];
            #pragma unroll
            for (int m = 0; m < 4; m++)
                #pragma unroll
                for (int r = 0; r < 4; r++) {
                    int row = m*16 + lh*4 + r;
                    x1s[row*136 + col] = (f16)silu_f(acc[n][m][r] + bb);
                }
        }
    }
    __syncthreads();

    // ---- layer 2: 64x128 @ 128x256 ----
    {
        floatx4 acc[4][4];
        #pragma unroll
        for (int n = 0; n < 4; n++)
            #pragma unroll
            for (int m = 0; m < 4; m++) acc[n][m] = (floatx4)0.0f;

        #pragma unroll
        for (int k0 = 0; k0 < 128; k0 += 32) {
            half8 a[4];
            #pragma unroll
            for (int m = 0; m < 4; m++)
                a[m] = *(const half8*)&x1s[(m*16 + lr)*136 + k0 + lh*8];
            #pragma unroll
            for (int n = 0; n < 4; n++) {
                int colb = wid*64 + n*16 + lr;
                half8 b = *(const half8*)&W2t[(size_t)colb*128 + k0 + lh*8];
                #pragma unroll
                for (int m = 0; m < 4; m++)
                    acc[n][m] = __builtin_amdgcn_mfma_f32_16x16x32_f16(a[m], b, acc[n][m], 0, 0, 0);
            }
        }
        #pragma unroll
        for (int n = 0; n < 4; n++) {
            int col = wid*64 + n*16 + lr;
            float bb = b2[col];
            #pragma unroll
            for (int m = 0; m < 4; m++)
                #pragma unroll
                for (int r = 0; r < 4; r++) {
                    int row = m*16 + lh*4 + r;
                    x2s[row*264 + col] = (f16)silu_f(acc[n][m][r] + bb);
                }
        }
    }
    __syncthreads();

    // ---- layer 3: 64x256 @ 256x384 ----
    floatx4 acc[6][4];
    #pragma unroll
    for (int n = 0; n < 6; n++)
        #pragma unroll
        for (int m = 0; m < 4; m++) acc[n][m] = (floatx4)0.0f;

    #pragma unroll
    for (int k0 = 0; k0 < 256; k0 += 32) {
        half8 a[4];
        #pragma unroll
        for (int m = 0; m < 4; m++)
            a[m] = *(const half8*)&x2s[(m*16 + lr)*264 + k0 + lh*8];
        #pragma unroll
        for (int n = 0; n < 6; n++) {
            int colb = wid*96 + n*16 + lr;
            half8 b = *(const half8*)&W3t[(size_t)colb*256 + k0 + lh*8];
            #pragma unroll
            for (int m = 0; m < 4; m++)
                acc[n][m] = __builtin_amdgcn_mfma_f32_16x16x32_f16(a[m], b, acc[n][m], 0, 0, 0);
        }
    }

    // ---- segmented scatter: LDS run-accumulator (aliases x bufs) ----
    __syncthreads();                         // all waves done reading x2s
    for (int i = t; i < R_MAX * 1280; i += 256) accum[i] = 0.f;
    __syncthreads();

    #pragma unroll
    for (int n = 0; n < 6; n++) {
        int col = wid*96 + n*16 + lr;
        int g = col >> 7;                    // wave-uniform per n
        int h = col & 127;
        const int pg = (g == 0) ? 1 : (g == 1) ? 3 : 6;
        const int bg = (g == 0) ? 0 : (g == 1) ? 1 : 4;
        float bb = b3[col];
        #pragma unroll
        for (int m = 0; m < 4; m++) {
            float psum[6];
            #pragma unroll
            for (int cc = 0; cc < 6; cc++) psum[cc] = 0.f;
            int currid = ridS[m*16 + lh*4];
            #pragma unroll
            for (int r = 0; r < 4; r++) {
                int e = m*16 + lh*4 + r;
                int rid = ridS[e];
                if (rid != currid) {
                    if (currid < R_MAX) {
                        #pragma unroll
                        for (int cc = 0; cc < 6; cc++)
                            if (cc < pg) atomicAdd(&accum[currid*1280 + (bg+cc)*128 + h], psum[cc]);
                    } else {
                        int s = runSrc[currid];
                        #pragma unroll
                        for (int cc = 0; cc < 6; cc++)
                            if (cc < pg) atomicAdd(&msg[(size_t)(bg+cc)*NH + (size_t)s*HD + h], psum[cc]);
                    }
                    #pragma unroll
                    for (int cc = 0; cc < 6; cc++) psum[cc] = 0.f;
                    currid = rid;
                }
                float v = silu_f(acc[n][m][r] + bb) * Cs[e];
                size_t db = (size_t)dstS[e] * HD + h;
                #pragma unroll
                for (int cc = 0; cc < 6; cc++)
                    if (cc < pg) psum[cc] = fmaf(v, Yc[(size_t)(bg+cc)*NH + db], psum[cc]);
            }
            if (currid < R_MAX) {
                #pragma unroll
                for (int cc = 0; cc < 6; cc++)
                    if (cc < pg) atomicAdd(&accum[currid*1280 + (bg+cc)*128 + h], psum[cc]);
            } else {
                int s = runSrc[currid];
                #pragma unroll
                for (int cc = 0; cc < 6; cc++)
                    if (cc < pg) atomicAdd(&msg[(size_t)(bg+cc)*NH + (size_t)s*HD + h], psum[cc]);
            }
        }
    }
    __syncthreads();

    // flush runs: interior runs (fully contained in block) use plain stores
    int nr  = nrunsS;
    int nrc = (nr < R_MAX) ? nr : R_MAX;
    for (int q = 0; q < nrc; q++) {
        int s = runSrc[q];
        bool interior = (q > 0) && (q < nr - 1);
        for (int i = t; i < 1280; i += 256) {
            int plane = i >> 7, h2 = i & 127;
            float val = accum[q*1280 + i];
            float* p = &msg[(size_t)plane*NH + (size_t)s*HD + h2];
            if (interior) *p = val;
            else atomicAdd(p, val);
        }
    }
}

// ---------------------------------------------------------------------------
// K4: T = msg@Y + Y@msg, decompose, normalize -> premix fields
// ---------------------------------------------------------------------------
__global__ __launch_bounds__(256) void combine(const float* __restrict__ msg,
                                               const float* __restrict__ Yc,
                                               float* __restrict__ pre) {
    int idx = blockIdx.x * 256 + threadIdx.x;
    if (idx >= NH) return;

    float mI  = msg[0*NH + idx];
    float ma0 = msg[1*NH + idx], ma1 = msg[2*NH + idx], ma2 = msg[3*NH + idx];
    float ms00 = msg[4*NH + idx], ms11 = msg[5*NH + idx], ms22 = msg[6*NH + idx];
    float ms01 = msg[7*NH + idx], ms02 = msg[8*NH + idx], ms12 = msg[9*NH + idx];

    float yI  = Yc[0*NH + idx];
    float ya0 = Yc[1*NH + idx], ya1 = Yc[2*NH + idx], ya2 = Yc[3*NH + idx];
    float ys00 = Yc[4*NH + idx], ys11 = Yc[5*NH + idx], ys22 = Yc[6*NH + idx];
    float ys01 = Yc[7*NH + idx], ys02 = Yc[8*NH + idx], ys12 = Yc[9*NH + idx];

    float M[3][3] = {
        { mI + ms00,  ms01 - ma2, ms02 + ma1 },
        { ms01 + ma2, mI + ms11,  ms12 - ma0 },
        { ms02 - ma1, ms12 + ma0, mI + ms22  } };
    float Y[3][3] = {
        { yI + ys00,  ys01 - ya2, ys02 + ya1 },
        { ys01 + ya2, yI + ys11,  ys12 - ya0 },
        { ys02 - ya1, ys12 + ya0, yI + ys22  } };

    float T[3][3];
    #pragma unroll
    for (int r = 0; r < 3; r++)
        #pragma unroll
        for (int c = 0; c < 3; c++) {
            float acc = 0.f;
            #pragma unroll
            for (int k = 0; k < 3; k++)
                acc += M[r][k] * Y[k][c] + Y[r][k] * M[k][c];
            T[r][c] = acc;
        }

    float tr3 = (T[0][0] + T[1][1] + T[2][2]) * (1.0f / 3.0f);
    float nsq = 0.f;
    #pragma unroll
    for (int r = 0; r < 3; r++)
        #pragma unroll
        for (int c = 0; c < 3; c++) nsq = fmaf(T[r][c], T[r][c], nsq);
    float inv = 1.0f / (nsq + 1.0f);

    pre[0*NH + idx] = tr3 * inv;
    pre[1*NH + idx] = 0.5f * (T[2][1] - T[1][2]) * inv;
    pre[2*NH + idx] = 0.5f * (T[0][2] - T[2][0]) * inv;
    pre[3*NH + idx] = 0.5f * (T[1][0] - T[0][1]) * inv;
    pre[4*NH + idx] = (T[0][0] - tr3) * inv;
    pre[5*NH + idx] = (T[1][1] - tr3) * inv;
    pre[6*NH + idx] = (T[2][2] - tr3) * inv;
    pre[7*NH + idx] = 0.5f * (T[0][1] + T[1][0]) * inv;
    pre[8*NH + idx] = 0.5f * (T[0][2] + T[2][0]) * inv;
    pre[9*NH + idx] = 0.5f * (T[1][2] + T[2][1]) * inv;
}

// ---------------------------------------------------------------------------
// K6: dX from postmix fields; out = Xn + dX + dX@dX
// ---------------------------------------------------------------------------
__global__ __launch_bounds__(256) void final_out(const float* __restrict__ post,
                                                 const float* __restrict__ X,
                                                 float* __restrict__ out) {
    int idx = blockIdx.x * 256 + threadIdx.x;
    if (idx >= NH) return;

    float dI  = post[0*NH + idx];
    float da0 = post[1*NH + idx], da1 = post[2*NH + idx], da2 = post[3*NH + idx];
    float ds00 = post[4*NH + idx], ds11 = post[5*NH + idx], ds22 = post[6*NH + idx];
    float ds01 = post[7*NH + idx], ds02 = post[8*NH + idx], ds12 = post[9*NH + idx];

    float D[3][3] = {
        { dI + ds00,  ds01 - da2, ds02 + da1 },
        { ds01 + da2, dI + ds11,  ds12 - da0 },
        { ds02 - da1, ds12 + da0, dI + ds22  } };

    const float* xp = X + (size_t)idx * 9;
    float x[9];
    #pragma unroll
    for (int i = 0; i < 9; i++) x[i] = xp[i];
    float nsq = 0.f;
    #pragma unroll
    for (int i = 0; i < 9; i++) nsq = fmaf(x[i], x[i], nsq);
    float inv = 1.0f / (nsq + 1.0f);

    float* op = out + (size_t)idx * 9;
    #pragma unroll
    for (int r = 0; r < 3; r++)
        #pragma unroll
        for (int c = 0; c < 3; c++) {
            float p = 0.f;
            #pragma unroll
            for (int k = 0; k < 3; k++) p = fmaf(D[r][k], D[k][c], p);
            op[r*3 + c] = x[r*3 + c] * inv + D[r][c] + p;
        }
}

// ---------------------------------------------------------------------------
extern "C" void kernel_launch(void* const* d_in, const int* in_sizes, int n_in,
                              void* d_out, int out_size, void* d_ws, size_t ws_size,
                              hipStream_t stream) {
    const float* X       = (const float*)d_in[0];
    const float* charges = (const float*)d_in[1];
    const float* ew      = (const float*)d_in[2];
    const float* ea      = (const float*)d_in[3];
    const float* W1      = (const float*)d_in[4];
    const float* b1      = (const float*)d_in[5];
    const float* W2      = (const float*)d_in[6];
    const float* b2      = (const float*)d_in[7];
    const float* W3      = (const float*)d_in[8];
    const float* b3      = (const float*)d_in[9];
    const float* Wt      = (const float*)d_in[10];
    const int*   eidx    = (const int*)d_in[11];
    float* out = (float*)d_out;

    float* compA = (float*)d_ws;                    // premix fields   (51.2 MB)
    float* compB = compA + (size_t)10 * NH;         // postmix / Y     (51.2 MB)
    float* compM = compB + (size_t)10 * NH;         // message accum   (51.2 MB)
    f16*   w1t   = (f16*)(compM + (size_t)10 * NH); // fp16 weights (272 KB)
    f16*   w2t   = w1t + 128*64;
    f16*   w3t   = w2t + 256*128;
    int*   hist   = (int*)(w3t + 384*256);
    int*   offs   = hist + NND;
    int*   cursor = offs + NND;
    int*   perm   = cursor + NND;
    int*   ssrc   = perm + NE;
    int*   sdst   = ssrc + NE;

    hipMemsetAsync(compM, 0, (size_t)10 * NH * sizeof(float), stream);
    hipMemsetAsync(hist, 0, NND * sizeof(int), stream);

    w_prep<<<544, 256, 0, stream>>>(W1, W2, W3, w1t, w2t, w3t);
    node_prep<<<NH / 256, 256, 0, stream>>>(X, compA);

    hist_kernel<<<(NE + 255) / 256, 256, 0, stream>>>(eidx, hist);
    scan_kernel<<<1, 1024, 0, stream>>>(hist, offs, cursor);
    scatter_kernel<<<(NE + 255) / 256, 256, 0, stream>>>(eidx, cursor, perm, ssrc, sdst);

    dim3 gmix((6 * NND + 63) / 64, 3);
    mix_gemm<<<gmix, 256, 0, stream>>>(compA, Wt, compB, 0, 1, 2);

    edge_mlp_sorted<<<NE / 64, 256, 0, stream>>>(ea, charges, ew,
                                                 perm, ssrc, sdst,
                                                 w1t, b1, w2t, b2, w3t, b3,
                                                 compB, compM);

    combine<<<NH / 256, 256, 0, stream>>>(compM, compB, compA);

    mix_gemm<<<gmix, 256, 0, stream>>>(compA, Wt, compB, 3, 4, 5);

    final_out<<<NH / 256, 256, 0, stream>>>(compB, X, out);
}

// Round 5
// 575.325 us; speedup vs baseline: 2.5304x; 2.4529x over previous
//
#include <hip/hip_runtime.h>
#include <math.h>

#define NND 10000
#define NE  160000
#define HD  128
#define NH  (NND*HD)   // 1,280,000

typedef _Float16 f16;
typedef _Float16 half8 __attribute__((ext_vector_type(8)));
typedef float floatx4 __attribute__((ext_vector_type(4)));

__device__ __forceinline__ float silu_f(float v) {
    return v * (1.0f / (1.0f + __expf(-v)));
}

// ---------------------------------------------------------------------------
// K0: weights -> fp16, transposed to [N][K] for contiguous B-fragment loads
// ---------------------------------------------------------------------------
__global__ __launch_bounds__(256) void w_prep(const float* __restrict__ W1,
                                              const float* __restrict__ W2,
                                              const float* __restrict__ W3,
                                              f16* __restrict__ w1t,
                                              f16* __restrict__ w2t,
                                              f16* __restrict__ w3t) {
    int id = blockIdx.x * 256 + threadIdx.x;
    if (id < 128*64) { int n = id >> 6, k = id & 63;  w1t[id] = (f16)W1[k*128 + n]; return; }
    id -= 128*64;
    if (id < 256*128) { int n = id >> 7, k = id & 127; w2t[id] = (f16)W2[k*256 + n]; return; }
    id -= 256*128;
    if (id < 384*256) { int n = id >> 8, k = id & 255; w3t[id] = (f16)W3[k*384 + n]; }
}

// ---------------------------------------------------------------------------
// Counting sort of edges by src: histogram -> scan -> scatter
// ---------------------------------------------------------------------------
__global__ __launch_bounds__(256) void hist_kernel(const int* __restrict__ eidx,
                                                   int* __restrict__ hist) {
    int e = blockIdx.x * 256 + threadIdx.x;
    if (e < NE) atomicAdd(&hist[eidx[e]], 1);
}

__global__ __launch_bounds__(1024) void scan_kernel(const int* __restrict__ hist,
                                                    int* __restrict__ offs,
                                                    int* __restrict__ cursor) {
    __shared__ int sums[1024];
    int t = threadIdx.x;
    int base = t * 10;
    int loc[10]; int s = 0;
    #pragma unroll
    for (int i = 0; i < 10; i++) {
        int v = (base + i < NND) ? hist[base + i] : 0;
        loc[i] = s; s += v;
    }
    sums[t] = s;
    __syncthreads();
    for (int off = 1; off < 1024; off <<= 1) {
        int v = (t >= off) ? sums[t - off] : 0;
        __syncthreads();
        sums[t] += v;
        __syncthreads();
    }
    int basesum = (t > 0) ? sums[t - 1] : 0;
    #pragma unroll
    for (int i = 0; i < 10; i++)
        if (base + i < NND) { offs[base + i] = basesum + loc[i]; cursor[base + i] = basesum + loc[i]; }
}

__global__ __launch_bounds__(256) void scatter_kernel(const int* __restrict__ eidx,
                                                      int* __restrict__ cursor,
                                                      int* __restrict__ perm,
                                                      int* __restrict__ ssrc,
                                                      int* __restrict__ sdst) {
    int e = blockIdx.x * 256 + threadIdx.x;
    if (e >= NE) return;
    int s = eidx[e], d = eidx[NE + e];
    int pos = atomicAdd(&cursor[s], 1);
    perm[pos] = e; ssrc[pos] = s; sdst[pos] = d;
}

// ---------------------------------------------------------------------------
// K1: normalize X, decompose into 10 scalar fields [f][n][h]
// ---------------------------------------------------------------------------
__global__ __launch_bounds__(256) void node_prep(const float* __restrict__ X,
                                                 float* __restrict__ comp) {
    int idx = blockIdx.x * 256 + threadIdx.x;
    if (idx >= NH) return;
    const float* xp = X + (size_t)idx * 9;
    float x[9];
    #pragma unroll
    for (int i = 0; i < 9; i++) x[i] = xp[i];
    float nsq = 0.f;
    #pragma unroll
    for (int i = 0; i < 9; i++) nsq = fmaf(x[i], x[i], nsq);
    float inv = 1.0f / (nsq + 1.0f);
    #pragma unroll
    for (int i = 0; i < 9; i++) x[i] *= inv;

    float I0  = (x[0] + x[4] + x[8]) * (1.0f / 3.0f);
    float a0  = 0.5f * (x[7] - x[5]);
    float a1  = 0.5f * (x[2] - x[6]);
    float a2  = 0.5f * (x[3] - x[1]);
    float s00 = x[0] - I0;
    float s11 = x[4] - I0;
    float s22 = x[8] - I0;
    float s01 = 0.5f * (x[1] + x[3]);
    float s02 = 0.5f * (x[2] + x[6]);
    float s12 = 0.5f * (x[5] + x[7]);

    comp[0*NH + idx] = I0;
    comp[1*NH + idx] = a0;  comp[2*NH + idx] = a1;  comp[3*NH + idx] = a2;
    comp[4*NH + idx] = s00; comp[5*NH + idx] = s11; comp[6*NH + idx] = s22;
    comp[7*NH + idx] = s01; comp[8*NH + idx] = s02; comp[9*NH + idx] = s12;
}

// ---------------------------------------------------------------------------
// K2: channel mix GEMM (fp32 VALU), [10*NND][128] x [128][128] grouped
// ---------------------------------------------------------------------------
__global__ __launch_bounds__(256) void mix_gemm(const float* __restrict__ A,
                                                const float* __restrict__ Wt,
                                                float* __restrict__ C,
                                                int w0, int w1, int w2) {
    const int g = blockIdx.y;
    const int baseRow = (g == 0) ? 0   : (g == 1 ? NND     : 4*NND);
    const int Mg      = (g == 0) ? NND : (g == 1 ? 3*NND   : 6*NND);
    const int row0 = blockIdx.x * 64;
    if (row0 >= Mg) return;
    const int wi = (g == 0) ? w0 : (g == 1 ? w1 : w2);
    const float* B  = Wt + (size_t)wi * HD * HD;
    const float* Ab = A + (size_t)baseRow * HD;
    float* Cb = C + (size_t)baseRow * HD;

    __shared__ float As[32][65];
    __shared__ float Bs[32][128];

    const int t  = threadIdx.x;
    const int tx = t & 31;
    const int ty = t >> 5;

    float acc[8][4];
    #pragma unroll
    for (int i = 0; i < 8; i++)
        #pragma unroll
        for (int j = 0; j < 4; j++) acc[i][j] = 0.0f;

    for (int k0 = 0; k0 < HD; k0 += 32) {
        #pragma unroll
        for (int i = 0; i < 8; i++) {
            int lin = t + 256 * i;
            int r = lin >> 5, kk = lin & 31;
            int rr = row0 + r; if (rr >= Mg) rr = Mg - 1;
            As[kk][r] = Ab[(size_t)rr * HD + k0 + kk];
        }
        #pragma unroll
        for (int i = 0; i < 16; i++) {
            int lin = t + 256 * i;
            int kr = lin >> 7, c = lin & 127;
            Bs[kr][c] = B[(size_t)(k0 + kr) * HD + c];
        }
        __syncthreads();
        #pragma unroll
        for (int k = 0; k < 32; k++) {
            float a[8];
            #pragma unroll
            for (int i = 0; i < 8; i++) a[i] = As[k][ty*8 + i];
            float4 bv = *(const float4*)&Bs[k][tx*4];
            #pragma unroll
            for (int i = 0; i < 8; i++) {
                acc[i][0] = fmaf(a[i], bv.x, acc[i][0]);
                acc[i][1] = fmaf(a[i], bv.y, acc[i][1]);
                acc[i][2] = fmaf(a[i], bv.z, acc[i][2]);
                acc[i][3] = fmaf(a[i], bv.w, acc[i][3]);
            }
        }
        __syncthreads();
    }
    #pragma unroll
    for (int i = 0; i < 8; i++) {
        int rr = row0 + ty*8 + i;
        if (rr < Mg) {
            float4 v = make_float4(acc[i][0], acc[i][1], acc[i][2], acc[i][3]);
            *(float4*)&Cb[(size_t)rr * HD + tx*4] = v;
        }
    }
}

// ---------------------------------------------------------------------------
// K3a: edge MLP via fp16 MFMA over SORTED edges of node chunk [n0,n1)
// -> vbuf[3][VC][128] (fp16), slot = p - offs[n0].
// 64 edges/block, 4 waves, 50 KB LDS pool -> 3 blocks/CU.
// ---------------------------------------------------------------------------
__global__ __launch_bounds__(256, 3) void edge_mlp_v(
    const float* __restrict__ edge_attr, const float* __restrict__ charges,
    const float* __restrict__ edge_weight,
    const int* __restrict__ offs,
    const int* __restrict__ perm, const int* __restrict__ ssrc, const int* __restrict__ sdst,
    const f16* __restrict__ W1t, const float* __restrict__ b1,
    const f16* __restrict__ W2t, const float* __restrict__ b2,
    const f16* __restrict__ W3t, const float* __restrict__ b3,
    f16* __restrict__ vbuf, int n0, int n1, int VC)
{
    __shared__ __align__(16) char pool[51200];
    f16* x1s = (f16*)pool;                 // 17408 B (K=128, row stride 136)
    f16* x2s = (f16*)(pool + 17408);       // 33792 B (K=256, row stride 264)
    f16* x0s = x2s;                        // aliases x2s head; dead before x2s written
    f16* stage = (f16*)pool;               // 64*392*2 = 50176 B (whole pool, after MFMAs)

    __shared__ int   srcS[64];
    __shared__ int   dstS[64];
    __shared__ int   permS[64];
    __shared__ float Cs[64];

    const int pbase = offs[n0];
    const int pend  = (n1 >= NND) ? NE : offs[n1];
    const int eb    = blockIdx.x * 64;        // slot base within chunk
    if (pbase + eb >= pend) return;

    const int t   = threadIdx.x;
    const int l   = t & 63;
    const int wid = t >> 6;
    const int lr  = l & 15;
    const int lh  = l >> 4;

    if (t < 64) {
        int pe = pbase + eb + t;
        if (pe > NE - 1) pe = NE - 1;         // clamp reads (tail garbage unread)
        int eo = perm[pe];
        permS[t] = eo;
        srcS[t]  = ssrc[pe];
        dstS[t]  = sdst[pe];
        float w = edge_weight[eo];
        float c = 0.5f * (cosf(w * (float)(M_PI / 4.5)) + 1.0f);
        Cs[t] = (w < 4.5f) ? c : 0.0f;
    }
    __syncthreads();

    // stage inputs as fp16: [attr(32) | charges[src](16) | charges[dst](16)]
    #pragma unroll
    for (int i = 0; i < 16; i++) {
        int lin = t + 256 * i;
        int e = lin >> 6, col = lin & 63;
        float v;
        if (col < 32)      v = edge_attr[(size_t)permS[e] * 32 + col];
        else if (col < 48) v = charges[(size_t)srcS[e] * 16 + (col - 32)];
        else               v = charges[(size_t)dstS[e] * 16 + (col - 48)];
        x0s[e * 72 + col] = (f16)v;
    }
    __syncthreads();

    // ---- layer 1: 64x64 @ 64x128 ----
    {
        floatx4 acc[2][4];
        #pragma unroll
        for (int n = 0; n < 2; n++)
            #pragma unroll
            for (int m = 0; m < 4; m++) acc[n][m] = (floatx4)0.0f;

        #pragma unroll
        for (int k0 = 0; k0 < 64; k0 += 32) {
            half8 a[4];
            #pragma unroll
            for (int m = 0; m < 4; m++)
                a[m] = *(const half8*)&x0s[(m*16 + lr)*72 + k0 + lh*8];
            #pragma unroll
            for (int n = 0; n < 2; n++) {
                int colb = wid*32 + n*16 + lr;
                half8 b = *(const half8*)&W1t[(size_t)colb*64 + k0 + lh*8];
                #pragma unroll
                for (int m = 0; m < 4; m++)
                    acc[n][m] = __builtin_amdgcn_mfma_f32_16x16x32_f16(a[m], b, acc[n][m], 0, 0, 0);
            }
        }
        __syncthreads();          // x0s (aliased) fully read before x1s writes
        #pragma unroll
        for (int n = 0; n < 2; n++) {
            int col = wid*32 + n*16 + lr;
            float bb = b1[col];
            #pragma unroll
            for (int m = 0; m < 4; m++)
                #pragma unroll
                for (int r = 0; r < 4; r++) {
                    int row = m*16 + lh*4 + r;
                    x1s[row*136 + col] = (f16)silu_f(acc[n][m][r] + bb);
                }
        }
    }
    __syncthreads();

    // ---- layer 2: 64x128 @ 128x256 ----
    {
        floatx4 acc[4][4];
        #pragma unroll
        for (int n = 0; n < 4; n++)
            #pragma unroll
            for (int m = 0; m < 4; m++) acc[n][m] = (floatx4)0.0f;

        #pragma unroll
        for (int k0 = 0; k0 < 128; k0 += 32) {
            half8 a[4];
            #pragma unroll
            for (int m = 0; m < 4; m++)
                a[m] = *(const half8*)&x1s[(m*16 + lr)*136 + k0 + lh*8];
            #pragma unroll
            for (int n = 0; n < 4; n++) {
                int colb = wid*64 + n*16 + lr;
                half8 b = *(const half8*)&W2t[(size_t)colb*128 + k0 + lh*8];
                #pragma unroll
                for (int m = 0; m < 4; m++)
                    acc[n][m] = __builtin_amdgcn_mfma_f32_16x16x32_f16(a[m], b, acc[n][m], 0, 0, 0);
            }
        }
        #pragma unroll
        for (int n = 0; n < 4; n++) {
            int col = wid*64 + n*16 + lr;
            float bb = b2[col];
            #pragma unroll
            for (int m = 0; m < 4; m++)
                #pragma unroll
                for (int r = 0; r < 4; r++) {
                    int row = m*16 + lh*4 + r;
                    x2s[row*264 + col] = (f16)silu_f(acc[n][m][r] + bb);
                }
        }
    }
    __syncthreads();

    // ---- layer 3: 64x256 @ 256x384 ----
    floatx4 acc[6][4];
    #pragma unroll
    for (int n = 0; n < 6; n++)
        #pragma unroll
        for (int m = 0; m < 4; m++) acc[n][m] = (floatx4)0.0f;

    #pragma unroll
    for (int k0 = 0; k0 < 256; k0 += 32) {
        half8 a[4];
        #pragma unroll
        for (int m = 0; m < 4; m++)
            a[m] = *(const half8*)&x2s[(m*16 + lr)*264 + k0 + lh*8];
        #pragma unroll
        for (int n = 0; n < 6; n++) {
            int colb = wid*96 + n*16 + lr;
            half8 b = *(const half8*)&W3t[(size_t)colb*256 + k0 + lh*8];
            #pragma unroll
            for (int m = 0; m < 4; m++)
                acc[n][m] = __builtin_amdgcn_mfma_f32_16x16x32_f16(a[m], b, acc[n][m], 0, 0, 0);
        }
    }
    __syncthreads();                       // all waves done reading x2s

    // stage v in LDS [64][392] (row = [3][128] + 8 pad), then vectorized copy
    #pragma unroll
    for (int n = 0; n < 6; n++) {
        int col = wid*96 + n*16 + lr;
        int g = col >> 7, h = col & 127;
        float bb = b3[col];
        #pragma unroll
        for (int m = 0; m < 4; m++)
            #pragma unroll
            for (int r = 0; r < 4; r++) {
                int e = m*16 + lh*4 + r;
                stage[e*392 + g*128 + h] = (f16)(silu_f(acc[n][m][r] + bb) * Cs[e]);
            }
    }
    __syncthreads();

    #pragma unroll
    for (int i = 0; i < 12; i++) {
        int c = t + 256 * i;
        int e = c / 48, j = c - e * 48;
        int g = j >> 4, h0 = (j & 15) * 8;
        half8 v = *(const half8*)&stage[e*392 + j*8];
        *(half8*)&vbuf[((size_t)g*VC + (size_t)(eb + e))*HD + h0] = v;
    }
}

// ---------------------------------------------------------------------------
// K3b: per-src-node gather-reduce + FUSED combine. Block = 1 node, 128 thr.
// psum in registers, zero atomics, zero LDS; writes premix fields directly.
// ---------------------------------------------------------------------------
__global__ __launch_bounds__(128) void scatter_combine(
    const int* __restrict__ offs, const int* __restrict__ ends,
    const int* __restrict__ sdst, const f16* __restrict__ vbuf,
    const float* __restrict__ Yc, float* __restrict__ pre,
    int n0, int VC)
{
    const int s = n0 + blockIdx.x;
    const int h = threadIdx.x;
    const int pbase = offs[n0];
    const int p0 = offs[s], p1 = ends[s];

    float ps[10];
    #pragma unroll
    for (int c = 0; c < 10; c++) ps[c] = 0.f;

    int p = p0;
    for (; p + 1 < p1; p += 2) {
        int sl0 = p - pbase, sl1 = sl0 + 1;
        int d0 = sdst[p], d1 = sdst[p + 1];
        const float* y0 = Yc + (size_t)d0 * HD + h;
        const float* y1 = Yc + (size_t)d1 * HD + h;
        float va0 = (float)vbuf[((size_t)0*VC + sl0)*HD + h];
        float vb0 = (float)vbuf[((size_t)1*VC + sl0)*HD + h];
        float vc0 = (float)vbuf[((size_t)2*VC + sl0)*HD + h];
        float va1 = (float)vbuf[((size_t)0*VC + sl1)*HD + h];
        float vb1 = (float)vbuf[((size_t)1*VC + sl1)*HD + h];
        float vc1 = (float)vbuf[((size_t)2*VC + sl1)*HD + h];
        float y0r[10], y1r[10];
        #pragma unroll
        for (int c = 0; c < 10; c++) { y0r[c] = y0[(size_t)c*NH]; y1r[c] = y1[(size_t)c*NH]; }
        ps[0] = fmaf(va0, y0r[0], ps[0]);
        #pragma unroll
        for (int c = 1; c < 4; c++)  ps[c] = fmaf(vb0, y0r[c], ps[c]);
        #pragma unroll
        for (int c = 4; c < 10; c++) ps[c] = fmaf(vc0, y0r[c], ps[c]);
        ps[0] = fmaf(va1, y1r[0], ps[0]);
        #pragma unroll
        for (int c = 1; c < 4; c++)  ps[c] = fmaf(vb1, y1r[c], ps[c]);
        #pragma unroll
        for (int c = 4; c < 10; c++) ps[c] = fmaf(vc1, y1r[c], ps[c]);
    }
    if (p < p1) {
        int sl0 = p - pbase;
        int d0 = sdst[p];
        const float* y0 = Yc + (size_t)d0 * HD + h;
        float va0 = (float)vbuf[((size_t)0*VC + sl0)*HD + h];
        float vb0 = (float)vbuf[((size_t)1*VC + sl0)*HD + h];
        float vc0 = (float)vbuf[((size_t)2*VC + sl0)*HD + h];
        float y0r[10];
        #pragma unroll
        for (int c = 0; c < 10; c++) y0r[c] = y0[(size_t)c*NH];
        ps[0] = fmaf(va0, y0r[0], ps[0]);
        #pragma unroll
        for (int c = 1; c < 4; c++)  ps[c] = fmaf(vb0, y0r[c], ps[c]);
        #pragma unroll
        for (int c = 4; c < 10; c++) ps[c] = fmaf(vc0, y0r[c], ps[c]);
    }

    // ---- fused combine: T = M@Y + Y@M, decompose, normalize ----
    const size_t idx = (size_t)s * HD + h;
    float yI  = Yc[0*(size_t)NH + idx];
    float ya0 = Yc[1*(size_t)NH + idx], ya1 = Yc[2*(size_t)NH + idx], ya2 = Yc[3*(size_t)NH + idx];
    float ys00 = Yc[4*(size_t)NH + idx], ys11 = Yc[5*(size_t)NH + idx], ys22 = Yc[6*(size_t)NH + idx];
    float ys01 = Yc[7*(size_t)NH + idx], ys02 = Yc[8*(size_t)NH + idx], ys12 = Yc[9*(size_t)NH + idx];

    float M[3][3] = {
        { ps[0] + ps[4],  ps[7] - ps[3],  ps[8] + ps[2] },
        { ps[7] + ps[3],  ps[0] + ps[5],  ps[9] - ps[1] },
        { ps[8] - ps[2],  ps[9] + ps[1],  ps[0] + ps[6] } };
    float Y[3][3] = {
        { yI + ys00,  ys01 - ya2, ys02 + ya1 },
        { ys01 + ya2, yI + ys11,  ys12 - ya0 },
        { ys02 - ya1, ys12 + ya0, yI + ys22  } };

    float T[3][3];
    #pragma unroll
    for (int r = 0; r < 3; r++)
        #pragma unroll
        for (int c = 0; c < 3; c++) {
            float acc = 0.f;
            #pragma unroll
            for (int k = 0; k < 3; k++)
                acc += M[r][k] * Y[k][c] + Y[r][k] * M[k][c];
            T[r][c] = acc;
        }

    float tr3 = (T[0][0] + T[1][1] + T[2][2]) * (1.0f / 3.0f);
    float nsq = 0.f;
    #pragma unroll
    for (int r = 0; r < 3; r++)
        #pragma unroll
        for (int c = 0; c < 3; c++) nsq = fmaf(T[r][c], T[r][c], nsq);
    float inv = 1.0f / (nsq + 1.0f);

    pre[0*(size_t)NH + idx] = tr3 * inv;
    pre[1*(size_t)NH + idx] = 0.5f * (T[2][1] - T[1][2]) * inv;
    pre[2*(size_t)NH + idx] = 0.5f * (T[0][2] - T[2][0]) * inv;
    pre[3*(size_t)NH + idx] = 0.5f * (T[1][0] - T[0][1]) * inv;
    pre[4*(size_t)NH + idx] = (T[0][0] - tr3) * inv;
    pre[5*(size_t)NH + idx] = (T[1][1] - tr3) * inv;
    pre[6*(size_t)NH + idx] = (T[2][2] - tr3) * inv;
    pre[7*(size_t)NH + idx] = 0.5f * (T[0][1] + T[1][0]) * inv;
    pre[8*(size_t)NH + idx] = 0.5f * (T[0][2] + T[2][0]) * inv;
    pre[9*(size_t)NH + idx] = 0.5f * (T[1][2] + T[2][1]) * inv;
}

// ---------------------------------------------------------------------------
// K6: dX from postmix fields; out = Xn + dX + dX@dX
// ---------------------------------------------------------------------------
__global__ __launch_bounds__(256) void final_out(const float* __restrict__ post,
                                                 const float* __restrict__ X,
                                                 float* __restrict__ out) {
    int idx = blockIdx.x * 256 + threadIdx.x;
    if (idx >= NH) return;

    float dI  = post[0*NH + idx];
    float da0 = post[1*NH + idx], da1 = post[2*NH + idx], da2 = post[3*NH + idx];
    float ds00 = post[4*NH + idx], ds11 = post[5*NH + idx], ds22 = post[6*NH + idx];
    float ds01 = post[7*NH + idx], ds02 = post[8*NH + idx], ds12 = post[9*NH + idx];

    float D[3][3] = {
        { dI + ds00,  ds01 - da2, ds02 + da1 },
        { ds01 + da2, dI + ds11,  ds12 - da0 },
        { ds02 - da1, ds12 + da0, dI + ds22  } };

    const float* xp = X + (size_t)idx * 9;
    float x[9];
    #pragma unroll
    for (int i = 0; i < 9; i++) x[i] = xp[i];
    float nsq = 0.f;
    #pragma unroll
    for (int i = 0; i < 9; i++) nsq = fmaf(x[i], x[i], nsq);
    float inv = 1.0f / (nsq + 1.0f);

    float* op = out + (size_t)idx * 9;
    #pragma unroll
    for (int r = 0; r < 3; r++)
        #pragma unroll
        for (int c = 0; c < 3; c++) {
            float p = 0.f;
            #pragma unroll
            for (int k = 0; k < 3; k++) p = fmaf(D[r][k], D[k][c], p);
            op[r*3 + c] = x[r*3 + c] * inv + D[r][c] + p;
        }
}

// ---------------------------------------------------------------------------
extern "C" void kernel_launch(void* const* d_in, const int* in_sizes, int n_in,
                              void* d_out, int out_size, void* d_ws, size_t ws_size,
                              hipStream_t stream) {
    const float* X       = (const float*)d_in[0];
    const float* charges = (const float*)d_in[1];
    const float* ew      = (const float*)d_in[2];
    const float* ea      = (const float*)d_in[3];
    const float* W1      = (const float*)d_in[4];
    const float* b1      = (const float*)d_in[5];
    const float* W2      = (const float*)d_in[6];
    const float* b2      = (const float*)d_in[7];
    const float* W3      = (const float*)d_in[8];
    const float* b3      = (const float*)d_in[9];
    const float* Wt      = (const float*)d_in[10];
    const int*   eidx    = (const int*)d_in[11];
    float* out = (float*)d_out;

    float* compA = (float*)d_ws;                    // premix / pre fields (51.2 MB)
    float* compB = compA + (size_t)10 * NH;         // Y / post fields     (51.2 MB)
    f16*   w1t   = (f16*)(compB + (size_t)10 * NH); // fp16 weights (272 KB)
    f16*   w2t   = w1t + 128*64;
    f16*   w3t   = w2t + 256*128;
    int*   hist   = (int*)(w3t + 384*256);
    int*   offs   = hist + NND;
    int*   cursor = offs + NND;                     // run-end after scatter
    int*   perm   = cursor + NND;
    int*   ssrc   = perm + NE;
    int*   sdst   = ssrc + NE;
    f16*   vbuf   = (f16*)(sdst + NE);              // [3][VC][128] fp16, chunked

    // choose chunk count from actual ws_size (host constant -> deterministic)
    size_t used = (size_t)((char*)vbuf - (char*)d_ws);
    int Q, VC;
    if      (used + (size_t)160000 * 384 * 2 <= ws_size) { Q = 1; VC = 160000; }
    else if (used + (size_t) 84480 * 384 * 2 <= ws_size) { Q = 2; VC = 84480;  }
    else if (used + (size_t) 48000 * 384 * 2 <= ws_size) { Q = 4; VC = 48000;  }
    else                                                 { Q = 8; VC = 24320;  }

    hipMemsetAsync(hist, 0, NND * sizeof(int), stream);

    w_prep<<<544, 256, 0, stream>>>(W1, W2, W3, w1t, w2t, w3t);
    node_prep<<<NH / 256, 256, 0, stream>>>(X, compA);

    hist_kernel<<<(NE + 255) / 256, 256, 0, stream>>>(eidx, hist);
    scan_kernel<<<1, 1024, 0, stream>>>(hist, offs, cursor);
    scatter_kernel<<<(NE + 255) / 256, 256, 0, stream>>>(eidx, cursor, perm, ssrc, sdst);

    dim3 gmix((6 * NND + 63) / 64, 3);
    mix_gemm<<<gmix, 256, 0, stream>>>(compA, Wt, compB, 0, 1, 2);

    const int nodesPer = NND / Q;
    for (int q = 0; q < Q; q++) {
        int n0 = q * nodesPer, n1 = n0 + nodesPer;
        edge_mlp_v<<<VC / 64, 256, 0, stream>>>(ea, charges, ew, offs,
                                                perm, ssrc, sdst,
                                                w1t, b1, w2t, b2, w3t, b3,
                                                vbuf, n0, n1, VC);
        scatter_combine<<<nodesPer, 128, 0, stream>>>(offs, cursor, sdst, vbuf,
                                                      compB, compA, n0, VC);
    }

    mix_gemm<<<gmix, 256, 0, stream>>>(compA, Wt, compB, 3, 4, 5);

    final_out<<<NH / 256, 256, 0, stream>>>(compB, X, out);
}

// Round 6
// 423.645 us; speedup vs baseline: 3.4364x; 1.3580x over previous
//
#include <hip/hip_runtime.h>
#include <math.h>

#define NND 10000
#define NE  160000
#define HD  128
#define NH  (NND*HD)   // 1,280,000

typedef _Float16 f16;
typedef _Float16 half8 __attribute__((ext_vector_type(8)));
typedef float floatx4 __attribute__((ext_vector_type(4)));

__device__ __forceinline__ float silu_f(float v) {
    return v * (1.0f / (1.0f + __expf(-v)));
}

// ---------------------------------------------------------------------------
// K0: weights -> fp16, transposed to [N][K] for contiguous B-fragment loads.
// W1 64->128, W2 128->256, W3 256->384, Wt 6x[128][128].
// ---------------------------------------------------------------------------
__global__ __launch_bounds__(256) void w_prep(const float* __restrict__ W1,
                                              const float* __restrict__ W2,
                                              const float* __restrict__ W3,
                                              const float* __restrict__ Wt,
                                              f16* __restrict__ w1t,
                                              f16* __restrict__ w2t,
                                              f16* __restrict__ w3t,
                                              f16* __restrict__ wtT) {
    int id = blockIdx.x * 256 + threadIdx.x;
    if (id < 128*64) { int n = id >> 6, k = id & 63;  w1t[id] = (f16)W1[k*128 + n]; return; }
    id -= 128*64;
    if (id < 256*128) { int n = id >> 7, k = id & 127; w2t[id] = (f16)W2[k*256 + n]; return; }
    id -= 256*128;
    if (id < 384*256) { int n = id >> 8, k = id & 255; w3t[id] = (f16)W3[k*384 + n]; return; }
    id -= 384*256;
    if (id < 6*128*128) {
        int wi = id >> 14, rem = id & 16383;
        int n = rem >> 7, k = rem & 127;
        wtT[(size_t)wi*16384 + n*128 + k] = (f16)Wt[(size_t)wi*16384 + k*128 + n];
    }
}

// ---------------------------------------------------------------------------
// Counting sort of edges by src: histogram -> scan -> scatter
// ---------------------------------------------------------------------------
__global__ __launch_bounds__(256) void hist_kernel(const int* __restrict__ eidx,
                                                   int* __restrict__ hist) {
    int e = blockIdx.x * 256 + threadIdx.x;
    if (e < NE) atomicAdd(&hist[eidx[e]], 1);
}

__global__ __launch_bounds__(1024) void scan_kernel(const int* __restrict__ hist,
                                                    int* __restrict__ offs,
                                                    int* __restrict__ cursor) {
    __shared__ int sums[1024];
    int t = threadIdx.x;
    int base = t * 10;
    int loc[10]; int s = 0;
    #pragma unroll
    for (int i = 0; i < 10; i++) {
        int v = (base + i < NND) ? hist[base + i] : 0;
        loc[i] = s; s += v;
    }
    sums[t] = s;
    __syncthreads();
    for (int off = 1; off < 1024; off <<= 1) {
        int v = (t >= off) ? sums[t - off] : 0;
        __syncthreads();
        sums[t] += v;
        __syncthreads();
    }
    int basesum = (t > 0) ? sums[t - 1] : 0;
    #pragma unroll
    for (int i = 0; i < 10; i++)
        if (base + i < NND) { offs[base + i] = basesum + loc[i]; cursor[base + i] = basesum + loc[i]; }
}

__global__ __launch_bounds__(256) void scatter_kernel(const int* __restrict__ eidx,
                                                      int* __restrict__ cursor,
                                                      int* __restrict__ perm,
                                                      int* __restrict__ ssrc,
                                                      int* __restrict__ sdst) {
    int e = blockIdx.x * 256 + threadIdx.x;
    if (e >= NE) return;
    int s = eidx[e], d = eidx[NE + e];
    int pos = atomicAdd(&cursor[s], 1);
    perm[pos] = e; ssrc[pos] = s; sdst[pos] = d;
}

// ---------------------------------------------------------------------------
// K1: normalize X, decompose into 10 scalar fields [f][n][h] (f16)
// ---------------------------------------------------------------------------
__global__ __launch_bounds__(256) void node_prep(const float* __restrict__ X,
                                                 f16* __restrict__ comp) {
    int idx = blockIdx.x * 256 + threadIdx.x;
    if (idx >= NH) return;
    const float* xp = X + (size_t)idx * 9;
    float x[9];
    #pragma unroll
    for (int i = 0; i < 9; i++) x[i] = xp[i];
    float nsq = 0.f;
    #pragma unroll
    for (int i = 0; i < 9; i++) nsq = fmaf(x[i], x[i], nsq);
    float inv = 1.0f / (nsq + 1.0f);
    #pragma unroll
    for (int i = 0; i < 9; i++) x[i] *= inv;

    float I0  = (x[0] + x[4] + x[8]) * (1.0f / 3.0f);
    float a0  = 0.5f * (x[7] - x[5]);
    float a1  = 0.5f * (x[2] - x[6]);
    float a2  = 0.5f * (x[3] - x[1]);
    float s00 = x[0] - I0;
    float s11 = x[4] - I0;
    float s22 = x[8] - I0;
    float s01 = 0.5f * (x[1] + x[3]);
    float s02 = 0.5f * (x[2] + x[6]);
    float s12 = 0.5f * (x[5] + x[7]);

    comp[0*NH + idx] = (f16)I0;
    comp[1*NH + idx] = (f16)a0;  comp[2*NH + idx] = (f16)a1;  comp[3*NH + idx] = (f16)a2;
    comp[4*NH + idx] = (f16)s00; comp[5*NH + idx] = (f16)s11; comp[6*NH + idx] = (f16)s22;
    comp[7*NH + idx] = (f16)s01; comp[8*NH + idx] = (f16)s02; comp[9*NH + idx] = (f16)s12;
}

// ---------------------------------------------------------------------------
// K2: channel-mix GEMM via fp16 MFMA. A [10*NND][128] f16 plane-major rows;
// grouped rows share Wt: g0=[0,N) wi=w0, g1=[N,4N) w1, g2=[4N,10N) w2.
// BM=64, full N=128, 4 waves each own 16 rows. Optionally writes a
// node-interleaved f16 copy Ch[node][10][128] for the gather kernel.
// ---------------------------------------------------------------------------
__global__ __launch_bounds__(256) void mix_mfma(const f16* __restrict__ A,
                                                const f16* __restrict__ WtT,
                                                float* __restrict__ C,
                                                f16* __restrict__ Ch,
                                                int w0, int w1, int w2, int writeCh) {
    const int g = blockIdx.y;
    const int baseRow = (g == 0) ? 0   : (g == 1 ? NND   : 4*NND);
    const int Mg      = (g == 0) ? NND : (g == 1 ? 3*NND : 6*NND);
    const int row0 = blockIdx.x * 64;
    if (row0 >= Mg) return;
    const int wi = (g == 0) ? w0 : (g == 1 ? w1 : w2);
    const f16* B = WtT + (size_t)wi * 128 * 128;

    __shared__ f16 As[64 * 136];   // 64 rows, stride 136 f16 (16B-aligned pad)

    const int t = threadIdx.x;
    const int l = t & 63, wid = t >> 6, lr = l & 15, lh = l >> 4;

    // stage A tile 64x128 f16 (coalesced half8)
    #pragma unroll
    for (int i = 0; i < 4; i++) {
        int id = t + 256 * i;             // 1024 half8s
        int r = id >> 4, ch = id & 15;
        int rr = row0 + r; if (rr >= Mg) rr = Mg - 1;
        *(half8*)&As[r*136 + ch*8] =
            *(const half8*)&A[((size_t)baseRow + rr) * HD + ch*8];
    }
    __syncthreads();

    floatx4 acc[8];
    #pragma unroll
    for (int n = 0; n < 8; n++) acc[n] = (floatx4)0.0f;

    #pragma unroll
    for (int k0 = 0; k0 < 128; k0 += 32) {
        half8 a = *(const half8*)&As[(wid*16 + lr)*136 + k0 + lh*8];
        #pragma unroll
        for (int n = 0; n < 8; n++) {
            half8 b = *(const half8*)&B[(size_t)(n*16 + lr)*128 + k0 + lh*8];
            acc[n] = __builtin_amdgcn_mfma_f32_16x16x32_f16(a, b, acc[n], 0, 0, 0);
        }
    }

    #pragma unroll
    for (int n = 0; n < 8; n++) {
        #pragma unroll
        for (int r = 0; r < 4; r++) {
            int gl = row0 + wid*16 + lh*4 + r;
            if (gl < Mg) {
                size_t grow = (size_t)baseRow + gl;
                int col = n*16 + lr;
                float val = acc[n][r];
                C[grow * HD + col] = val;
                if (writeCh) {
                    int plane = (int)(grow / NND);
                    int node  = (int)(grow - (size_t)plane * NND);
                    Ch[((size_t)node * 10 + plane) * HD + col] = (f16)val;
                }
            }
        }
    }
}

// ---------------------------------------------------------------------------
// K3a: edge MLP via fp16 MFMA over SORTED edges of node chunk [n0,n1)
// -> vbuf[3][VC][128] (fp16), slot = p - offs[n0].
// 64 edges/block, 4 waves, 50 KB LDS pool -> 3 blocks/CU.
// ---------------------------------------------------------------------------
__global__ __launch_bounds__(256, 3) void edge_mlp_v(
    const float* __restrict__ edge_attr, const float* __restrict__ charges,
    const float* __restrict__ edge_weight,
    const int* __restrict__ offs,
    const int* __restrict__ perm, const int* __restrict__ ssrc, const int* __restrict__ sdst,
    const f16* __restrict__ W1t, const float* __restrict__ b1,
    const f16* __restrict__ W2t, const float* __restrict__ b2,
    const f16* __restrict__ W3t, const float* __restrict__ b3,
    f16* __restrict__ vbuf, int n0, int n1, int VC)
{
    __shared__ __align__(16) char pool[51200];
    f16* x1s = (f16*)pool;                 // 17408 B (K=128, row stride 136)
    f16* x2s = (f16*)(pool + 17408);       // 33792 B (K=256, row stride 264)
    f16* x0s = x2s;                        // aliases x2s head; dead before x2s written
    f16* stage = (f16*)pool;               // 64*392*2 = 50176 B (whole pool, after MFMAs)

    __shared__ int   srcS[64];
    __shared__ int   dstS[64];
    __shared__ int   permS[64];
    __shared__ float Cs[64];

    const int pbase = offs[n0];
    const int pend  = (n1 >= NND) ? NE : offs[n1];
    const int eb    = blockIdx.x * 64;        // slot base within chunk
    if (pbase + eb >= pend) return;

    const int t   = threadIdx.x;
    const int l   = t & 63;
    const int wid = t >> 6;
    const int lr  = l & 15;
    const int lh  = l >> 4;

    if (t < 64) {
        int pe = pbase + eb + t;
        if (pe > NE - 1) pe = NE - 1;         // clamp reads (tail garbage unread)
        int eo = perm[pe];
        permS[t] = eo;
        srcS[t]  = ssrc[pe];
        dstS[t]  = sdst[pe];
        float w = edge_weight[eo];
        float c = 0.5f * (cosf(w * (float)(M_PI / 4.5)) + 1.0f);
        Cs[t] = (w < 4.5f) ? c : 0.0f;
    }
    __syncthreads();

    // stage inputs as fp16: [attr(32) | charges[src](16) | charges[dst](16)]
    #pragma unroll
    for (int i = 0; i < 16; i++) {
        int lin = t + 256 * i;
        int e = lin >> 6, col = lin & 63;
        float v;
        if (col < 32)      v = edge_attr[(size_t)permS[e] * 32 + col];
        else if (col < 48) v = charges[(size_t)srcS[e] * 16 + (col - 32)];
        else               v = charges[(size_t)dstS[e] * 16 + (col - 48)];
        x0s[e * 72 + col] = (f16)v;
    }
    __syncthreads();

    // ---- layer 1: 64x64 @ 64x128 ----
    {
        floatx4 acc[2][4];
        #pragma unroll
        for (int n = 0; n < 2; n++)
            #pragma unroll
            for (int m = 0; m < 4; m++) acc[n][m] = (floatx4)0.0f;

        #pragma unroll
        for (int k0 = 0; k0 < 64; k0 += 32) {
            half8 a[4];
            #pragma unroll
            for (int m = 0; m < 4; m++)
                a[m] = *(const half8*)&x0s[(m*16 + lr)*72 + k0 + lh*8];
            #pragma unroll
            for (int n = 0; n < 2; n++) {
                int colb = wid*32 + n*16 + lr;
                half8 b = *(const half8*)&W1t[(size_t)colb*64 + k0 + lh*8];
                #pragma unroll
                for (int m = 0; m < 4; m++)
                    acc[n][m] = __builtin_amdgcn_mfma_f32_16x16x32_f16(a[m], b, acc[n][m], 0, 0, 0);
            }
        }
        __syncthreads();          // x0s (aliased) fully read before x1s writes
        #pragma unroll
        for (int n = 0; n < 2; n++) {
            int col = wid*32 + n*16 + lr;
            float bb = b1[col];
            #pragma unroll
            for (int m = 0; m < 4; m++)
                #pragma unroll
                for (int r = 0; r < 4; r++) {
                    int row = m*16 + lh*4 + r;
                    x1s[row*136 + col] = (f16)silu_f(acc[n][m][r] + bb);
                }
        }
    }
    __syncthreads();

    // ---- layer 2: 64x128 @ 128x256 ----
    {
        floatx4 acc[4][4];
        #pragma unroll
        for (int n = 0; n < 4; n++)
            #pragma unroll
            for (int m = 0; m < 4; m++) acc[n][m] = (floatx4)0.0f;

        #pragma unroll
        for (int k0 = 0; k0 < 128; k0 += 32) {
            half8 a[4];
            #pragma unroll
            for (int m = 0; m < 4; m++)
                a[m] = *(const half8*)&x1s[(m*16 + lr)*136 + k0 + lh*8];
            #pragma unroll
            for (int n = 0; n < 4; n++) {
                int colb = wid*64 + n*16 + lr;
                half8 b = *(const half8*)&W2t[(size_t)colb*128 + k0 + lh*8];
                #pragma unroll
                for (int m = 0; m < 4; m++)
                    acc[n][m] = __builtin_amdgcn_mfma_f32_16x16x32_f16(a[m], b, acc[n][m], 0, 0, 0);
            }
        }
        #pragma unroll
        for (int n = 0; n < 4; n++) {
            int col = wid*64 + n*16 + lr;
            float bb = b2[col];
            #pragma unroll
            for (int m = 0; m < 4; m++)
                #pragma unroll
                for (int r = 0; r < 4; r++) {
                    int row = m*16 + lh*4 + r;
                    x2s[row*264 + col] = (f16)silu_f(acc[n][m][r] + bb);
                }
        }
    }
    __syncthreads();

    // ---- layer 3: 64x256 @ 256x384 ----
    floatx4 acc[6][4];
    #pragma unroll
    for (int n = 0; n < 6; n++)
        #pragma unroll
        for (int m = 0; m < 4; m++) acc[n][m] = (floatx4)0.0f;

    #pragma unroll
    for (int k0 = 0; k0 < 256; k0 += 32) {
        half8 a[4];
        #pragma unroll
        for (int m = 0; m < 4; m++)
            a[m] = *(const half8*)&x2s[(m*16 + lr)*264 + k0 + lh*8];
        #pragma unroll
        for (int n = 0; n < 6; n++) {
            int colb = wid*96 + n*16 + lr;
            half8 b = *(const half8*)&W3t[(size_t)colb*256 + k0 + lh*8];
            #pragma unroll
            for (int m = 0; m < 4; m++)
                acc[n][m] = __builtin_amdgcn_mfma_f32_16x16x32_f16(a[m], b, acc[n][m], 0, 0, 0);
        }
    }
    __syncthreads();                       // all waves done reading x2s

    // stage v in LDS [64][392] (row = [3][128] + 8 pad), then vectorized copy
    #pragma unroll
    for (int n = 0; n < 6; n++) {
        int col = wid*96 + n*16 + lr;
        int g = col >> 7, h = col & 127;
        float bb = b3[col];
        #pragma unroll
        for (int m = 0; m < 4; m++)
            #pragma unroll
            for (int r = 0; r < 4; r++) {
                int e = m*16 + lh*4 + r;
                stage[e*392 + g*128 + h] = (f16)(silu_f(acc[n][m][r] + bb) * Cs[e]);
            }
    }
    __syncthreads();

    #pragma unroll
    for (int i = 0; i < 12; i++) {
        int c = t + 256 * i;
        int e = c / 48, j = c - e * 48;
        int g = j >> 4, h0 = (j & 15) * 8;
        half8 v = *(const half8*)&stage[e*392 + j*8];
        *(half8*)&vbuf[((size_t)g*VC + (size_t)(eb + e))*HD + h0] = v;
    }
}

// ---------------------------------------------------------------------------
// K3b: per-src-node gather-reduce + FUSED combine. Block = 1 node, 128 thr.
// Gathers Ych (f16, node-interleaved), own-node Y from Yc (f32).
// psum in registers, zero atomics, zero LDS; writes premix fields (f16).
// ---------------------------------------------------------------------------
__global__ __launch_bounds__(128) void scatter_combine(
    const int* __restrict__ offs, const int* __restrict__ ends,
    const int* __restrict__ sdst, const f16* __restrict__ vbuf,
    const f16* __restrict__ Ych, const float* __restrict__ Yc,
    f16* __restrict__ pre, int n0, int VC)
{
    const int s = n0 + blockIdx.x;
    const int h = threadIdx.x;
    const int pbase = offs[n0];
    const int p0 = offs[s], p1 = ends[s];

    float ps[10];
    #pragma unroll
    for (int c = 0; c < 10; c++) ps[c] = 0.f;

    int p = p0;
    for (; p + 1 < p1; p += 2) {
        int sl0 = p - pbase, sl1 = sl0 + 1;
        int d0 = sdst[p], d1 = sdst[p + 1];
        const f16* y0 = Ych + (size_t)d0 * 1280 + h;
        const f16* y1 = Ych + (size_t)d1 * 1280 + h;
        float va0 = (float)vbuf[((size_t)0*VC + sl0)*HD + h];
        float vb0 = (float)vbuf[((size_t)1*VC + sl0)*HD + h];
        float vc0 = (float)vbuf[((size_t)2*VC + sl0)*HD + h];
        float va1 = (float)vbuf[((size_t)0*VC + sl1)*HD + h];
        float vb1 = (float)vbuf[((size_t)1*VC + sl1)*HD + h];
        float vc1 = (float)vbuf[((size_t)2*VC + sl1)*HD + h];
        float y0r[10], y1r[10];
        #pragma unroll
        for (int c = 0; c < 10; c++) { y0r[c] = (float)y0[c*HD]; y1r[c] = (float)y1[c*HD]; }
        ps[0] = fmaf(va0, y0r[0], ps[0]);
        #pragma unroll
        for (int c = 1; c < 4; c++)  ps[c] = fmaf(vb0, y0r[c], ps[c]);
        #pragma unroll
        for (int c = 4; c < 10; c++) ps[c] = fmaf(vc0, y0r[c], ps[c]);
        ps[0] = fmaf(va1, y1r[0], ps[0]);
        #pragma unroll
        for (int c = 1; c < 4; c++)  ps[c] = fmaf(vb1, y1r[c], ps[c]);
        #pragma unroll
        for (int c = 4; c < 10; c++) ps[c] = fmaf(vc1, y1r[c], ps[c]);
    }
    if (p < p1) {
        int sl0 = p - pbase;
        int d0 = sdst[p];
        const f16* y0 = Ych + (size_t)d0 * 1280 + h;
        float va0 = (float)vbuf[((size_t)0*VC + sl0)*HD + h];
        float vb0 = (float)vbuf[((size_t)1*VC + sl0)*HD + h];
        float vc0 = (float)vbuf[((size_t)2*VC + sl0)*HD + h];
        float y0r[10];
        #pragma unroll
        for (int c = 0; c < 10; c++) y0r[c] = (float)y0[c*HD];
        ps[0] = fmaf(va0, y0r[0], ps[0]);
        #pragma unroll
        for (int c = 1; c < 4; c++)  ps[c] = fmaf(vb0, y0r[c], ps[c]);
        #pragma unroll
        for (int c = 4; c < 10; c++) ps[c] = fmaf(vc0, y0r[c], ps[c]);
    }

    // ---- fused combine: T = M@Y + Y@M, decompose, normalize ----
    const size_t idx = (size_t)s * HD + h;
    float yI  = Yc[0*(size_t)NH + idx];
    float ya0 = Yc[1*(size_t)NH + idx], ya1 = Yc[2*(size_t)NH + idx], ya2 = Yc[3*(size_t)NH + idx];
    float ys00 = Yc[4*(size_t)NH + idx], ys11 = Yc[5*(size_t)NH + idx], ys22 = Yc[6*(size_t)NH + idx];
    float ys01 = Yc[7*(size_t)NH + idx], ys02 = Yc[8*(size_t)NH + idx], ys12 = Yc[9*(size_t)NH + idx];

    float M[3][3] = {
        { ps[0] + ps[4],  ps[7] - ps[3],  ps[8] + ps[2] },
        { ps[7] + ps[3],  ps[0] + ps[5],  ps[9] - ps[1] },
        { ps[8] - ps[2],  ps[9] + ps[1],  ps[0] + ps[6] } };
    float Y[3][3] = {
        { yI + ys00,  ys01 - ya2, ys02 + ya1 },
        { ys01 + ya2, yI + ys11,  ys12 - ya0 },
        { ys02 - ya1, ys12 + ya0, yI + ys22  } };

    float T[3][3];
    #pragma unroll
    for (int r = 0; r < 3; r++)
        #pragma unroll
        for (int c = 0; c < 3; c++) {
            float acc = 0.f;
            #pragma unroll
            for (int k = 0; k < 3; k++)
                acc += M[r][k] * Y[k][c] + Y[r][k] * M[k][c];
            T[r][c] = acc;
        }

    float tr3 = (T[0][0] + T[1][1] + T[2][2]) * (1.0f / 3.0f);
    float nsq = 0.f;
    #pragma unroll
    for (int r = 0; r < 3; r++)
        #pragma unroll
        for (int c = 0; c < 3; c++) nsq = fmaf(T[r][c], T[r][c], nsq);
    float inv = 1.0f / (nsq + 1.0f);

    pre[0*(size_t)NH + idx] = (f16)(tr3 * inv);
    pre[1*(size_t)NH + idx] = (f16)(0.5f * (T[2][1] - T[1][2]) * inv);
    pre[2*(size_t)NH + idx] = (f16)(0.5f * (T[0][2] - T[2][0]) * inv);
    pre[3*(size_t)NH + idx] = (f16)(0.5f * (T[1][0] - T[0][1]) * inv);
    pre[4*(size_t)NH + idx] = (f16)((T[0][0] - tr3) * inv);
    pre[5*(size_t)NH + idx] = (f16)((T[1][1] - tr3) * inv);
    pre[6*(size_t)NH + idx] = (f16)((T[2][2] - tr3) * inv);
    pre[7*(size_t)NH + idx] = (f16)(0.5f * (T[0][1] + T[1][0]) * inv);
    pre[8*(size_t)NH + idx] = (f16)(0.5f * (T[0][2] + T[2][0]) * inv);
    pre[9*(size_t)NH + idx] = (f16)(0.5f * (T[1][2] + T[2][1]) * inv);
}

// ---------------------------------------------------------------------------
// K6: dX from postmix fields (f32); out = Xn + dX + dX@dX
// ---------------------------------------------------------------------------
__global__ __launch_bounds__(256) void final_out(const float* __restrict__ post,
                                                 const float* __restrict__ X,
                                                 float* __restrict__ out) {
    int idx = blockIdx.x * 256 + threadIdx.x;
    if (idx >= NH) return;

    float dI  = post[0*NH + idx];
    float da0 = post[1*NH + idx], da1 = post[2*NH + idx], da2 = post[3*NH + idx];
    float ds00 = post[4*NH + idx], ds11 = post[5*NH + idx], ds22 = post[6*NH + idx];
    float ds01 = post[7*NH + idx], ds02 = post[8*NH + idx], ds12 = post[9*NH + idx];

    float D[3][3] = {
        { dI + ds00,  ds01 - da2, ds02 + da1 },
        { ds01 + da2, dI + ds11,  ds12 - da0 },
        { ds02 - da1, ds12 + da0, dI + ds22  } };

    const float* xp = X + (size_t)idx * 9;
    float x[9];
    #pragma unroll
    for (int i = 0; i < 9; i++) x[i] = xp[i];
    float nsq = 0.f;
    #pragma unroll
    for (int i = 0; i < 9; i++) nsq = fmaf(x[i], x[i], nsq);
    float inv = 1.0f / (nsq + 1.0f);

    float* op = out + (size_t)idx * 9;
    #pragma unroll
    for (int r = 0; r < 3; r++)
        #pragma unroll
        for (int c = 0; c < 3; c++) {
            float p = 0.f;
            #pragma unroll
            for (int k = 0; k < 3; k++) p = fmaf(D[r][k], D[k][c], p);
            op[r*3 + c] = x[r*3 + c] * inv + D[r][c] + p;
        }
}

// ---------------------------------------------------------------------------
extern "C" void kernel_launch(void* const* d_in, const int* in_sizes, int n_in,
                              void* d_out, int out_size, void* d_ws, size_t ws_size,
                              hipStream_t stream) {
    const float* X       = (const float*)d_in[0];
    const float* charges = (const float*)d_in[1];
    const float* ew      = (const float*)d_in[2];
    const float* ea      = (const float*)d_in[3];
    const float* W1      = (const float*)d_in[4];
    const float* b1      = (const float*)d_in[5];
    const float* W2      = (const float*)d_in[6];
    const float* b2      = (const float*)d_in[7];
    const float* W3      = (const float*)d_in[8];
    const float* b3      = (const float*)d_in[9];
    const float* Wt      = (const float*)d_in[10];
    const int*   eidx    = (const int*)d_in[11];
    float* out = (float*)d_out;

    float* f32a  = (float*)d_ws;                    // Yc (mix1 out), then post (mix2 out): 51.2 MB
    f16*   fh16  = (f16*)(f32a + (size_t)10 * NH);  // comp (f16), then preh: 25.6 MB
    f16*   ych   = fh16 + (size_t)10 * NH;          // [NND][10][128] f16: 25.6 MB
    f16*   w1t   = ych + (size_t)10 * NH;
    f16*   w2t   = w1t + 128*64;
    f16*   w3t   = w2t + 256*128;
    f16*   wtT   = w3t + 384*256;                   // [6][128][128] f16
    int*   hist   = (int*)(wtT + 6*128*128);
    int*   offs   = hist + NND;
    int*   cursor = offs + NND;                     // run-end after scatter
    int*   perm   = cursor + NND;
    int*   ssrc   = perm + NE;
    int*   sdst   = ssrc + NE;
    f16*   vbuf   = (f16*)(sdst + NE);              // [3][VC][128] f16, chunked

    // choose chunk count from actual ws_size (host constant -> deterministic)
    size_t used = (size_t)((char*)vbuf - (char*)d_ws);
    int Q, VC;
    if      (used + (size_t)160000 * 384 * 2 <= ws_size) { Q = 1; VC = 160000; }
    else if (used + (size_t) 84480 * 384 * 2 <= ws_size) { Q = 2; VC = 84480;  }
    else if (used + (size_t) 48000 * 384 * 2 <= ws_size) { Q = 4; VC = 48000;  }
    else                                                 { Q = 8; VC = 24320;  }

    hipMemsetAsync(hist, 0, NND * sizeof(int), stream);

    w_prep<<<928, 256, 0, stream>>>(W1, W2, W3, Wt, w1t, w2t, w3t, wtT);
    node_prep<<<NH / 256, 256, 0, stream>>>(X, fh16);

    hist_kernel<<<(NE + 255) / 256, 256, 0, stream>>>(eidx, hist);
    scan_kernel<<<1, 1024, 0, stream>>>(hist, offs, cursor);
    scatter_kernel<<<(NE + 255) / 256, 256, 0, stream>>>(eidx, cursor, perm, ssrc, sdst);

    dim3 gmix((6 * NND + 63) / 64, 3);
    // mix #1: comp -> Yc (f32) + Ych (f16 node-interleaved)
    mix_mfma<<<gmix, 256, 0, stream>>>(fh16, wtT, f32a, ych, 0, 1, 2, 1);

    const int nodesPer = NND / Q;
    for (int q = 0; q < Q; q++) {
        int n0 = q * nodesPer, n1 = n0 + nodesPer;
        edge_mlp_v<<<VC / 64, 256, 0, stream>>>(ea, charges, ew, offs,
                                                perm, ssrc, sdst,
                                                w1t, b1, w2t, b2, w3t, b3,
                                                vbuf, n0, n1, VC);
        scatter_combine<<<nodesPer, 128, 0, stream>>>(offs, cursor, sdst, vbuf,
                                                      ych, f32a, fh16, n0, VC);
    }

    // mix #2: preh -> post (f32)
    mix_mfma<<<gmix, 256, 0, stream>>>(fh16, wtT, f32a, ych, 3, 4, 5, 0);

    final_out<<<NH / 256, 256, 0, stream>>>(f32a, X, out);
}